// Round 1
// 415.778 us; speedup vs baseline: 1.1614x; 1.1614x over previous
//
#include <hip/hip_runtime.h>

#define T_SEQ 2048
#define NHEADS 8
#define NKV 4
#define HD 256
#define WIN 512

typedef __bf16 bf16x8 __attribute__((ext_vector_type(8)));
typedef float f32x4 __attribute__((ext_vector_type(4)));

__device__ __forceinline__ float bf2f(unsigned short u) {
    return __uint_as_float(((unsigned int)u) << 16);
}
__device__ __forceinline__ unsigned short f2bf(float f) {
    unsigned int u = __float_as_uint(f);
    u += 0x7fffu + ((u >> 16) & 1u);
    return (unsigned short)(u >> 16);
}

#define GLOAD_LDS16(gptr, lptr)                                            \
    __builtin_amdgcn_global_load_lds(                                      \
        (const __attribute__((address_space(1))) unsigned int*)(gptr),     \
        (__attribute__((address_space(3))) unsigned int*)(lptr), 16, 0, 0)

// ------------------------------------------------------------- dtype detect
__global__ void detect_dtype(const unsigned short* __restrict__ x, int* flag) {
    int tid = threadIdx.x;
    int cnt = 0;
    for (int i = 0; i < 64; ++i) {
        unsigned short u = x[2 * (tid * 64 + i)];
        int e = (u >> 7) & 0xFF;
        cnt += (e >= 100 && e <= 140) ? 1 : 0;
    }
    #pragma unroll
    for (int o = 32; o >= 1; o >>= 1) cnt += __shfl_xor(cnt, o);
    if (tid == 0) *flag = (cnt > 2048) ? 1 : 0;
}

// ------------------------------------------------------------- convert
__global__ __launch_bounds__(256) void convert_to_bf16(
    const void* __restrict__ src, unsigned short* __restrict__ dst,
    const int* __restrict__ flag, int n)
{
    int i = (blockIdx.x * 256 + threadIdx.x) * 8;
    if (i >= n) return;
    if (*flag) {
        *(uint4*)&dst[i] = *(const uint4*)((const unsigned short*)src + i);
    } else {
        const float* s = (const float*)src + i;
        unsigned short v[8];
        #pragma unroll
        for (int j = 0; j < 8; ++j) v[j] = f2bf(s[j]);
        *(uint4*)&dst[i] = *(uint4*)v;
    }
}

// ------------------------------------------------------------- transpose+cvt
__global__ __launch_bounds__(256) void transpose_cvt(
    const void* __restrict__ src, unsigned short* __restrict__ dst,
    const int* __restrict__ flag, int R, int C)
{
    __shared__ unsigned short tile[32][33];
    const int t = threadIdx.x;
    const int c = t & 31, r8 = t >> 5;
    const int bx = blockIdx.x, by = blockIdx.y;
    const int isb = *flag;
    #pragma unroll
    for (int i = 0; i < 4; ++i) {
        int r = r8 + i * 8;
        size_t idx = (size_t)(by * 32 + r) * C + bx * 32 + c;
        tile[r][c] = isb ? ((const unsigned short*)src)[idx]
                         : f2bf(((const float*)src)[idx]);
    }
    __syncthreads();
    #pragma unroll
    for (int i = 0; i < 4; ++i) {
        int r = r8 + i * 8;
        dst[(size_t)(bx * 32 + r) * R + by * 32 + c] = tile[c][r];
    }
}

// ------------------------------------------------------------- GEMM (m97)
__global__ __launch_bounds__(256) void gemm_bf16(
    const unsigned short* __restrict__ A,
    const unsigned short* __restrict__ Bt,
    void* __restrict__ C,
    int M, int Ntot, int K, int n_base,
    const int* __restrict__ flag, int force_bf16)
{
    __shared__ __align__(16) unsigned short As[128 * 32];
    __shared__ __align__(16) unsigned short Bs[128 * 32];
    const int tid = threadIdx.x;
    const int n0 = blockIdx.x * 128;
    const int m0 = blockIdx.y * 128;
    const int wave = tid >> 6;
    const int lane = tid & 63;
    const int wm = (wave >> 1) * 64;
    const int wn = (wave & 1) * 64;
    const int quad = lane >> 4;
    const int l16 = lane & 15;
    const int obf = force_bf16 | *flag;

    f32x4 acc[4][4];
    #pragma unroll
    for (int i = 0; i < 4; ++i)
        #pragma unroll
        for (int j = 0; j < 4; ++j)
            acc[i][j] = f32x4{0.f, 0.f, 0.f, 0.f};

    for (int kk = 0; kk < K; kk += 32) {
        #pragma unroll
        for (int i = 0; i < 2; ++i) {
            int ch = tid + i * 256;
            int row = ch >> 2;
            int ko = (ch & 3) * 8;
            GLOAD_LDS16(&A[(size_t)(m0 + row) * K + kk + ko],  &As[ch * 8]);
            GLOAD_LDS16(&Bt[(size_t)(n0 + row) * K + kk + ko], &Bs[ch * 8]);
        }
        __syncthreads();
        bf16x8 af[4], bfr[4];
        #pragma unroll
        for (int mi = 0; mi < 4; ++mi)
            af[mi] = *(const bf16x8*)&As[(wm + mi * 16 + l16) * 32 + quad * 8];
        #pragma unroll
        for (int ni = 0; ni < 4; ++ni)
            bfr[ni] = *(const bf16x8*)&Bs[(wn + ni * 16 + l16) * 32 + quad * 8];
        #pragma unroll
        for (int mi = 0; mi < 4; ++mi)
            #pragma unroll
            for (int ni = 0; ni < 4; ++ni)
                acc[mi][ni] = __builtin_amdgcn_mfma_f32_16x16x32_bf16(
                    af[mi], bfr[ni], acc[mi][ni], 0, 0, 0);
        __syncthreads();
    }

    #pragma unroll
    for (int mi = 0; mi < 4; ++mi)
        #pragma unroll
        for (int ni = 0; ni < 4; ++ni)
            #pragma unroll
            for (int r = 0; r < 4; ++r) {
                int row = m0 + wm + mi * 16 + quad * 4 + r;
                int col = n_base + n0 + wn + ni * 16 + l16;
                size_t idx = (size_t)row * Ntot + col;
                if (obf) ((unsigned short*)C)[idx] = f2bf(acc[mi][ni][r]);
                else     ((float*)C)[idx]          = acc[mi][ni][r];
            }
}

// ------------------------------------------------------------- finalize
__global__ __launch_bounds__(256) void finalize_qk(
    unsigned short* __restrict__ qkv,
    const int* __restrict__ segment_pos,
    const unsigned short* __restrict__ scales)
{
    const int w = blockIdx.x * 4 + (threadIdx.x >> 6);
    const int lane = threadIdx.x & 63;
    const int b = w / (T_SEQ * 12);
    const int rem = w % (T_SEQ * 12);
    const int t = rem / 12;
    const int slot = rem % 12;
    const bool isq = slot < 8;
    const int col0 = isq ? slot * 256 : 2048 + (slot - 8) * 256;
    unsigned short* p = qkv + (size_t)(b * T_SEQ + t) * 4096 + col0;

    float e[4];
    #pragma unroll
    for (int j = 0; j < 4; ++j) e[j] = bf2f(p[lane + 64 * j]);
    float ss = e[0] * e[0] + e[1] * e[1] + e[2] * e[2] + e[3] * e[3];
    #pragma unroll
    for (int o = 32; o >= 1; o >>= 1) ss += __shfl_xor(ss, o);
    const float rn = rsqrtf(ss * (1.0f / 256.0f) + 1e-6f);
    const unsigned short* scp = scales + (isq ? 0 : 256);
    float nrm[4];
    #pragma unroll
    for (int j = 0; j < 4; ++j)
        nrm[j] = e[j] * rn * (1.0f + bf2f(scp[lane + 64 * j]));

    const int pos = segment_pos[b * T_SEQ + t];
    #pragma unroll
    for (int pp = 0; pp < 2; ++pp) {
        const int i = lane + 64 * pp;
        const float inv_ts = __expf((float)i * -0.07195578415606293f);
        float s, c;
        __sincosf((float)pos * inv_ts, &s, &c);
        const float x1 = nrm[pp], x2 = nrm[pp + 2];
        p[i]       = f2bf(x1 * c - x2 * s);
        p[i + 128] = f2bf(x2 * c + x1 * s);
    }
}

// ------------------------------------------------------------- V transpose
__global__ __launch_bounds__(256) void build_vt(
    const unsigned short* __restrict__ qkv, unsigned short* __restrict__ vt)
{
    __shared__ unsigned short tile[32][33];
    const int bkv = blockIdx.z;
    const int b = bkv >> 2, kv = bkv & 3;
    const int s0 = blockIdx.x * 32, d0 = blockIdx.y * 32;
    const int c = threadIdx.x & 31, r8 = threadIdx.x >> 5;
    #pragma unroll
    for (int i = 0; i < 4; ++i) {
        int r = r8 + i * 8;
        tile[r][c] = qkv[(size_t)(b * T_SEQ + s0 + r) * 4096 + 3072 + kv * 256 + d0 + c];
    }
    __syncthreads();
    #pragma unroll
    for (int i = 0; i < 4; ++i) {
        int r = r8 + i * 8;
        vt[((size_t)bkv * 256 + d0 + r) * T_SEQ + s0 + c] = tile[c][r];
    }
}

// ------------------------------------------------------------- MFMA attention
// Staging via global_load_lds with PRE-SWIZZLED global source (m173 pattern):
// LDS destination stays linear, so LDS contents are identical to the old
// register-staged swizzled layout and the read side is unchanged.
// This removes the ka[8]/va[8] uint4 prefetch arrays (64 VGPRs) that were
// spilling to scratch (253 MB/dispatch HBM writes at VGPR_Count=124).
#define PSTR 80
__global__ __launch_bounds__(256, 2) void attn_mfma(
    const unsigned short* __restrict__ qkv,
    const unsigned short* __restrict__ vt,
    unsigned short* __restrict__ out)
{
    __shared__ __align__(16) unsigned short SMEM[16384 + 16384 + 4 * 16 * PSTR];
    unsigned short* K_lds  = SMEM;            // 64 x 256 (swizzled)
    unsigned short* VT_lds = SMEM + 16384;    // 256 x 64 (swizzled)

    const int tid = threadIdx.x;
    const int wave = tid >> 6, lane = tid & 63;
    const int l16 = lane & 15, quad = lane >> 4;
    const int sw = l16 & 7;
    const int bkv = blockIdx.x & 7;           // XCD swizzle: same bkv -> same XCD
    const int qt  = blockIdx.x >> 3;
    const int b = bkv >> 2, kvh = bkv & 3;
    const int t0 = qt * 32;
    const int h = kvh * 2 + (wave >> 1);
    const int woff = (wave & 1) * 16;
    const int tq = t0 + woff + l16;
    unsigned short* P_lds = SMEM + 32768 + wave * 16 * PSTR;

    bf16x8 qf[8];
    {
        const unsigned short* qp =
            qkv + (size_t)(b * T_SEQ + tq) * 4096 + h * 256 + quad * 8;
        #pragma unroll
        for (int c = 0; c < 8; ++c) qf[c] = *(const bf16x8*)(qp + 32 * c);
    }

    f32x4 o[16];
    #pragma unroll
    for (int nt = 0; nt < 16; ++nt) o[nt] = f32x4{0.f, 0.f, 0.f, 0.f};
    float l_run = 0.f;

    int s_lo = t0 - (WIN - 1); if (s_lo < 0) s_lo = 0;
    const int s_base = s_lo & ~63;
    const int s_last = t0 + 31;
    const int tqmin = t0 + woff;
    const int tqmax = tqmin + 15;
    const int wlo   = tqmin - (WIN - 1);      // lowest key this wave can see
    const size_t kgbase = (size_t)b * T_SEQ * 4096 + 2048 + kvh * 256;
    const size_t vgbase = (size_t)bkv * 256 * T_SEQ;

    for (int sb = s_base; sb <= s_last; sb += 64) {
        __syncthreads();   // previous tile fully consumed

        // K tile: linear LDS dest, source column pre-swizzled so that
        // LDS[row*256 + e8*8] = K[row][(e8 ^ (row&7))*8 ..]
        #pragma unroll
        for (int i = 0; i < 8; ++i) {
            int ch = tid + 256 * i;
            int row = ch >> 5, e8 = ch & 31;
            GLOAD_LDS16(&qkv[kgbase + (size_t)(sb + row) * 4096
                             + ((e8 ^ (row & 7)) * 8)],
                        &K_lds[ch * 8]);
        }
        // VT tile: LDS[dr*64 + e8*8] = vt[dr][sb + (e8 ^ (dr&7))*8 ..]
        #pragma unroll
        for (int i = 0; i < 8; ++i) {
            int ch = tid + 256 * i;
            int dr = ch >> 3, e8 = ch & 7;
            GLOAD_LDS16(&vt[vgbase + (size_t)dr * T_SEQ + sb
                            + ((e8 ^ (dr & 7)) * 8)],
                        &VT_lds[ch * 8]);
        }
        __syncthreads();   // drains vmcnt(0): tile resident in LDS

        if (sb > tqmax || sb + 63 < wlo) continue;   // wave-uniform skip

        // S^T = K · Q^T
        f32x4 st[4];
        #pragma unroll
        for (int mt = 0; mt < 4; ++mt) st[mt] = f32x4{0.f, 0.f, 0.f, 0.f};
        __builtin_amdgcn_s_setprio(1);
        #pragma unroll
        for (int c = 0; c < 8; ++c) {
            bf16x8 kf[4];
            #pragma unroll
            for (int mt = 0; mt < 4; ++mt)
                kf[mt] = *(const bf16x8*)&K_lds[(mt * 16 + l16) * 256 + (((4 * c + quad) ^ sw) * 8)];
            #pragma unroll
            for (int mt = 0; mt < 4; ++mt)
                st[mt] = __builtin_amdgcn_mfma_f32_16x16x32_bf16(kf[mt], qf[c], st[mt], 0, 0, 0);
        }
        __builtin_amdgcn_s_setprio(0);

        // softcap + exp(static m=30); P -> LDS
        #pragma unroll
        for (int mt = 0; mt < 4; ++mt)
            #pragma unroll
            for (int r = 0; r < 4; ++r) {
                int sp = sb + mt * 16 + quad * 4 + r;
                float e2 = __expf(st[mt][r] * 0.0025f);         // exp(2*logits/800)
                float p = __expf(20.0f - 100.0f / (e2 + 1.0f)); // exp(softcap - 30)
                bool valid = (sp <= tq) && (tq - sp < WIN);
                p = valid ? p : 0.0f;
                l_run += p;
                P_lds[l16 * PSTR + mt * 16 + quad * 4 + r] = f2bf(p);
            }

        // O += P · V^T
        #pragma unroll
        for (int c = 0; c < 2; ++c) {
            bf16x8 pf = *(const bf16x8*)&P_lds[l16 * PSTR + 32 * c + quad * 8];
            __builtin_amdgcn_s_setprio(1);
            #pragma unroll
            for (int nt = 0; nt < 16; ++nt) {
                bf16x8 vf = *(const bf16x8*)&VT_lds[(nt * 16 + l16) * 64 + (((4 * c + quad) ^ sw) * 8)];
                o[nt] = __builtin_amdgcn_mfma_f32_16x16x32_bf16(pf, vf, o[nt], 0, 0, 0);
            }
            __builtin_amdgcn_s_setprio(0);
        }
    }

    l_run += __shfl_xor(l_run, 16);
    l_run += __shfl_xor(l_run, 32);
    float linv[4];
    #pragma unroll
    for (int r = 0; r < 4; ++r) linv[r] = 1.0f / __shfl(l_run, quad * 4 + r);

    // coalesced epilogue: O -> LDS (row-major 16x256, stride 264) -> dwordx4
    __syncthreads();
    unsigned short* W = SMEM + wave * (16 * 264);
    #pragma unroll
    for (int nt = 0; nt < 16; ++nt)
        #pragma unroll
        for (int r = 0; r < 4; ++r)
            W[(quad * 4 + r) * 264 + nt * 16 + l16] = f2bf(o[nt][r] * linv[r]);
    const int lr = lane >> 2, lc = (lane & 3) * 64;
    unsigned short* ob = out + (size_t)(b * T_SEQ + t0 + woff + lr) * 2048 + h * 256 + lc;
    #pragma unroll
    for (int j = 0; j < 8; ++j)
        *(uint4*)(ob + j * 8) = *(const uint4*)&W[lr * 264 + lc + j * 8];
}

// ------------------------------------------------------------- launch
extern "C" void kernel_launch(void* const* d_in, const int* in_sizes, int n_in,
                              void* d_out, int out_size, void* d_ws, size_t ws_size,
                              hipStream_t stream) {
    const void* x   = d_in[0];
    const int*  sp  = (const int*)d_in[1];
    const void* wq  = d_in[3];
    const void* wk  = d_in[4];
    const void* wv  = d_in[5];
    const void* wo  = d_in[6];
    const void* qsc = d_in[7];
    const void* ksc = d_in[8];

    unsigned short* ws = (unsigned short*)d_ws;
    int*            flag = (int*)ws;
    unsigned short* sbuf = ws + 1024;
    unsigned short* reg1 = ws + 2048;                      // 8,388,608 us
    unsigned short* reg2 = reg1 + (size_t)4096 * 2048;     // 4,194,304 us
    unsigned short* xhat = reg1;
    unsigned short* abuf = reg1;
    unsigned short* qkv  = (unsigned short*)d_out;

    dim3 blk(256);
    detect_dtype<<<1, 64, 0, stream>>>((const unsigned short*)x, flag);

    convert_to_bf16<<<4096, blk, 0, stream>>>(x,   xhat,       flag, 4096 * 2048);
    convert_to_bf16<<<1,    blk, 0, stream>>>(qsc, sbuf,       flag, 256);
    convert_to_bf16<<<1,    blk, 0, stream>>>(ksc, sbuf + 256, flag, 256);

    transpose_cvt<<<dim3(64, 64), blk, 0, stream>>>(wq, reg2, flag, 2048, 2048);
    gemm_bf16<<<dim3(16, 32), blk, 0, stream>>>(xhat, reg2, qkv,
                                                4096, 4096, 2048, 0, flag, 1);
    transpose_cvt<<<dim3(32, 64), blk, 0, stream>>>(wk, reg2,                     flag, 2048, 1024);
    transpose_cvt<<<dim3(32, 64), blk, 0, stream>>>(wv, reg2 + (size_t)1024*2048, flag, 2048, 1024);
    gemm_bf16<<<dim3(16, 32), blk, 0, stream>>>(xhat, reg2, qkv,
                                                4096, 4096, 2048, 2048, flag, 1);

    finalize_qk<<<12288, blk, 0, stream>>>(qkv, sp, sbuf);

    build_vt<<<dim3(64, 8, 8), blk, 0, stream>>>(qkv, reg2);
    attn_mfma<<<512, blk, 0, stream>>>(qkv, reg2, abuf);

    transpose_cvt<<<dim3(64, 64), blk, 0, stream>>>(wo, reg2, flag, 2048, 2048);
    gemm_bf16<<<dim3(16, 32), blk, 0, stream>>>(abuf, reg2, d_out,
                                                4096, 2048, 2048, 0, flag, 0);
}

// Round 2
// 400.556 us; speedup vs baseline: 1.2056x; 1.0380x over previous
//
#include <hip/hip_runtime.h>

#define T_SEQ 2048
#define NHEADS 8
#define NKV 4
#define HD 256
#define WIN 512

typedef __bf16 bf16x8 __attribute__((ext_vector_type(8)));
typedef float f32x4 __attribute__((ext_vector_type(4)));

__device__ __forceinline__ float bf2f(unsigned short u) {
    return __uint_as_float(((unsigned int)u) << 16);
}
__device__ __forceinline__ unsigned short f2bf(float f) {
    unsigned int u = __float_as_uint(f);
    u += 0x7fffu + ((u >> 16) & 1u);
    return (unsigned short)(u >> 16);
}

#define GLOAD_LDS16(gptr, lptr)                                            \
    __builtin_amdgcn_global_load_lds(                                      \
        (const __attribute__((address_space(1))) unsigned int*)(gptr),     \
        (__attribute__((address_space(3))) unsigned int*)(lptr), 16, 0, 0)

// ------------------------------------------------------------- dtype detect
__global__ void detect_dtype(const unsigned short* __restrict__ x, int* flag) {
    int tid = threadIdx.x;
    int cnt = 0;
    for (int i = 0; i < 64; ++i) {
        unsigned short u = x[2 * (tid * 64 + i)];
        int e = (u >> 7) & 0xFF;
        cnt += (e >= 100 && e <= 140) ? 1 : 0;
    }
    #pragma unroll
    for (int o = 32; o >= 1; o >>= 1) cnt += __shfl_xor(cnt, o);
    if (tid == 0) *flag = (cnt > 2048) ? 1 : 0;
}

// ------------------------------------------------------------- convert
__global__ __launch_bounds__(256) void convert_to_bf16(
    const void* __restrict__ src, unsigned short* __restrict__ dst,
    const int* __restrict__ flag, int n)
{
    int i = (blockIdx.x * 256 + threadIdx.x) * 8;
    if (i >= n) return;
    if (*flag) {
        *(uint4*)&dst[i] = *(const uint4*)((const unsigned short*)src + i);
    } else {
        const float* s = (const float*)src + i;
        unsigned short v[8];
        #pragma unroll
        for (int j = 0; j < 8; ++j) v[j] = f2bf(s[j]);
        *(uint4*)&dst[i] = *(uint4*)v;
    }
}

// ------------------------------------------------------------- transpose+cvt
__global__ __launch_bounds__(256) void transpose_cvt(
    const void* __restrict__ src, unsigned short* __restrict__ dst,
    const int* __restrict__ flag, int R, int C)
{
    __shared__ unsigned short tile[32][33];
    const int t = threadIdx.x;
    const int c = t & 31, r8 = t >> 5;
    const int bx = blockIdx.x, by = blockIdx.y;
    const int isb = *flag;
    #pragma unroll
    for (int i = 0; i < 4; ++i) {
        int r = r8 + i * 8;
        size_t idx = (size_t)(by * 32 + r) * C + bx * 32 + c;
        tile[r][c] = isb ? ((const unsigned short*)src)[idx]
                         : f2bf(((const float*)src)[idx]);
    }
    __syncthreads();
    #pragma unroll
    for (int i = 0; i < 4; ++i) {
        int r = r8 + i * 8;
        dst[(size_t)(bx * 32 + r) * R + by * 32 + c] = tile[c][r];
    }
}

// ------------------------------------------------------------- GEMM (m97)
__global__ __launch_bounds__(256) void gemm_bf16(
    const unsigned short* __restrict__ A,
    const unsigned short* __restrict__ Bt,
    void* __restrict__ C,
    int M, int Ntot, int K, int n_base,
    const int* __restrict__ flag, int force_bf16)
{
    __shared__ __align__(16) unsigned short As[128 * 32];
    __shared__ __align__(16) unsigned short Bs[128 * 32];
    const int tid = threadIdx.x;
    const int n0 = blockIdx.x * 128;
    const int m0 = blockIdx.y * 128;
    const int wave = tid >> 6;
    const int lane = tid & 63;
    const int wm = (wave >> 1) * 64;
    const int wn = (wave & 1) * 64;
    const int quad = lane >> 4;
    const int l16 = lane & 15;
    const int obf = force_bf16 | *flag;

    f32x4 acc[4][4];
    #pragma unroll
    for (int i = 0; i < 4; ++i)
        #pragma unroll
        for (int j = 0; j < 4; ++j)
            acc[i][j] = f32x4{0.f, 0.f, 0.f, 0.f};

    for (int kk = 0; kk < K; kk += 32) {
        #pragma unroll
        for (int i = 0; i < 2; ++i) {
            int ch = tid + i * 256;
            int row = ch >> 2;
            int ko = (ch & 3) * 8;
            GLOAD_LDS16(&A[(size_t)(m0 + row) * K + kk + ko],  &As[ch * 8]);
            GLOAD_LDS16(&Bt[(size_t)(n0 + row) * K + kk + ko], &Bs[ch * 8]);
        }
        __syncthreads();
        bf16x8 af[4], bfr[4];
        #pragma unroll
        for (int mi = 0; mi < 4; ++mi)
            af[mi] = *(const bf16x8*)&As[(wm + mi * 16 + l16) * 32 + quad * 8];
        #pragma unroll
        for (int ni = 0; ni < 4; ++ni)
            bfr[ni] = *(const bf16x8*)&Bs[(wn + ni * 16 + l16) * 32 + quad * 8];
        #pragma unroll
        for (int mi = 0; mi < 4; ++mi)
            #pragma unroll
            for (int ni = 0; ni < 4; ++ni)
                acc[mi][ni] = __builtin_amdgcn_mfma_f32_16x16x32_bf16(
                    af[mi], bfr[ni], acc[mi][ni], 0, 0, 0);
        __syncthreads();
    }

    #pragma unroll
    for (int mi = 0; mi < 4; ++mi)
        #pragma unroll
        for (int ni = 0; ni < 4; ++ni)
            #pragma unroll
            for (int r = 0; r < 4; ++r) {
                int row = m0 + wm + mi * 16 + quad * 4 + r;
                int col = n_base + n0 + wn + ni * 16 + l16;
                size_t idx = (size_t)row * Ntot + col;
                if (obf) ((unsigned short*)C)[idx] = f2bf(acc[mi][ni][r]);
                else     ((float*)C)[idx]          = acc[mi][ni][r];
            }
}

// ------------------------------------------------------------- finalize
__global__ __launch_bounds__(256) void finalize_qk(
    unsigned short* __restrict__ qkv,
    const int* __restrict__ segment_pos,
    const unsigned short* __restrict__ scales)
{
    const int w = blockIdx.x * 4 + (threadIdx.x >> 6);
    const int lane = threadIdx.x & 63;
    const int b = w / (T_SEQ * 12);
    const int rem = w % (T_SEQ * 12);
    const int t = rem / 12;
    const int slot = rem % 12;
    const bool isq = slot < 8;
    const int col0 = isq ? slot * 256 : 2048 + (slot - 8) * 256;
    unsigned short* p = qkv + (size_t)(b * T_SEQ + t) * 4096 + col0;

    float e[4];
    #pragma unroll
    for (int j = 0; j < 4; ++j) e[j] = bf2f(p[lane + 64 * j]);
    float ss = e[0] * e[0] + e[1] * e[1] + e[2] * e[2] + e[3] * e[3];
    #pragma unroll
    for (int o = 32; o >= 1; o >>= 1) ss += __shfl_xor(ss, o);
    const float rn = rsqrtf(ss * (1.0f / 256.0f) + 1e-6f);
    const unsigned short* scp = scales + (isq ? 0 : 256);
    float nrm[4];
    #pragma unroll
    for (int j = 0; j < 4; ++j)
        nrm[j] = e[j] * rn * (1.0f + bf2f(scp[lane + 64 * j]));

    const int pos = segment_pos[b * T_SEQ + t];
    #pragma unroll
    for (int pp = 0; pp < 2; ++pp) {
        const int i = lane + 64 * pp;
        const float inv_ts = __expf((float)i * -0.07195578415606293f);
        float s, c;
        __sincosf((float)pos * inv_ts, &s, &c);
        const float x1 = nrm[pp], x2 = nrm[pp + 2];
        p[i]       = f2bf(x1 * c - x2 * s);
        p[i + 128] = f2bf(x2 * c + x1 * s);
    }
}

// ------------------------------------------------------------- V transpose
__global__ __launch_bounds__(256) void build_vt(
    const unsigned short* __restrict__ qkv, unsigned short* __restrict__ vt)
{
    __shared__ unsigned short tile[32][33];
    const int bkv = blockIdx.z;
    const int b = bkv >> 2, kv = bkv & 3;
    const int s0 = blockIdx.x * 32, d0 = blockIdx.y * 32;
    const int c = threadIdx.x & 31, r8 = threadIdx.x >> 5;
    #pragma unroll
    for (int i = 0; i < 4; ++i) {
        int r = r8 + i * 8;
        tile[r][c] = qkv[(size_t)(b * T_SEQ + s0 + r) * 4096 + 3072 + kv * 256 + d0 + c];
    }
    __syncthreads();
    #pragma unroll
    for (int i = 0; i < 4; ++i) {
        int r = r8 + i * 8;
        vt[((size_t)bkv * 256 + d0 + r) * T_SEQ + s0 + c] = tile[c][r];
    }
}

// ------------------------------------------------------------- MFMA attention
#define PSTR 80
__global__ __launch_bounds__(256, 2) void attn_mfma(
    const unsigned short* __restrict__ qkv,
    const unsigned short* __restrict__ vt,
    unsigned short* __restrict__ out)
{
    __shared__ __align__(16) unsigned short SMEM[16384 + 16384 + 4 * 16 * PSTR];
    unsigned short* K_lds  = SMEM;            // 64 x 256 (swizzled)
    unsigned short* VT_lds = SMEM + 16384;    // 256 x 64 (swizzled)

    const int tid = threadIdx.x;
    const int wave = tid >> 6, lane = tid & 63;
    const int l16 = lane & 15, quad = lane >> 4;
    const int sw = l16 & 7;
    const int bkv = blockIdx.x & 7;           // XCD swizzle: same bkv -> same XCD
    const int qt  = blockIdx.x >> 3;
    const int b = bkv >> 2, kvh = bkv & 3;
    const int t0 = qt * 32;
    const int h = kvh * 2 + (wave >> 1);
    const int woff = (wave & 1) * 16;
    const int tq = t0 + woff + l16;
    unsigned short* P_lds = SMEM + 32768 + wave * 16 * PSTR;

    bf16x8 qf[8];
    {
        const unsigned short* qp =
            qkv + (size_t)(b * T_SEQ + tq) * 4096 + h * 256 + quad * 8;
        #pragma unroll
        for (int c = 0; c < 8; ++c) qf[c] = *(const bf16x8*)(qp + 32 * c);
    }

    f32x4 o[16];
    #pragma unroll
    for (int nt = 0; nt < 16; ++nt) o[nt] = f32x4{0.f, 0.f, 0.f, 0.f};
    float l_run = 0.f;

    int s_lo = t0 - (WIN - 1); if (s_lo < 0) s_lo = 0;
    const int s_base = s_lo & ~63;
    const int s_last = t0 + 31;
    const int tqmin = t0 + woff;
    const int tqmax = tqmin + 15;
    const int wlo   = tqmin - (WIN - 1);      // lowest key this wave can see
    const size_t kgbase = (size_t)b * T_SEQ * 4096 + 2048 + kvh * 256;
    const size_t vgbase = (size_t)bkv * 256 * T_SEQ;

    for (int sb = s_base; sb <= s_last; sb += 64) {
        __syncthreads();   // previous tile fully consumed

        // K tile: linear LDS dest, source column pre-swizzled (m173 pattern)
        #pragma unroll
        for (int i = 0; i < 8; ++i) {
            int ch = tid + 256 * i;
            int row = ch >> 5, e8 = ch & 31;
            GLOAD_LDS16(&qkv[kgbase + (size_t)(sb + row) * 4096
                             + ((e8 ^ (row & 7)) * 8)],
                        &K_lds[ch * 8]);
        }
        // VT tile
        #pragma unroll
        for (int i = 0; i < 8; ++i) {
            int ch = tid + 256 * i;
            int dr = ch >> 3, e8 = ch & 7;
            GLOAD_LDS16(&vt[vgbase + (size_t)dr * T_SEQ + sb
                            + ((e8 ^ (dr & 7)) * 8)],
                        &VT_lds[ch * 8]);
        }
        __syncthreads();   // drains vmcnt(0): tile resident in LDS

        if (sb > tqmax || sb + 63 < wlo) continue;   // wave-uniform skip

        // S^T = K · Q^T
        f32x4 st[4];
        #pragma unroll
        for (int mt = 0; mt < 4; ++mt) st[mt] = f32x4{0.f, 0.f, 0.f, 0.f};
        __builtin_amdgcn_s_setprio(1);
        #pragma unroll
        for (int c = 0; c < 8; ++c) {
            bf16x8 kf[4];
            #pragma unroll
            for (int mt = 0; mt < 4; ++mt)
                kf[mt] = *(const bf16x8*)&K_lds[(mt * 16 + l16) * 256 + (((4 * c + quad) ^ sw) * 8)];
            #pragma unroll
            for (int mt = 0; mt < 4; ++mt)
                st[mt] = __builtin_amdgcn_mfma_f32_16x16x32_bf16(kf[mt], qf[c], st[mt], 0, 0, 0);
        }
        __builtin_amdgcn_s_setprio(0);

        // softcap + exp(static m=30); P -> LDS
        #pragma unroll
        for (int mt = 0; mt < 4; ++mt)
            #pragma unroll
            for (int r = 0; r < 4; ++r) {
                int sp = sb + mt * 16 + quad * 4 + r;
                float e2 = __expf(st[mt][r] * 0.0025f);         // exp(2*logits/800)
                float p = __expf(20.0f - 100.0f / (e2 + 1.0f)); // exp(softcap - 30)
                bool valid = (sp <= tq) && (tq - sp < WIN);
                p = valid ? p : 0.0f;
                l_run += p;
                P_lds[l16 * PSTR + mt * 16 + quad * 4 + r] = f2bf(p);
            }

        // O += P · V^T
        #pragma unroll
        for (int c = 0; c < 2; ++c) {
            bf16x8 pf = *(const bf16x8*)&P_lds[l16 * PSTR + 32 * c + quad * 8];
            __builtin_amdgcn_s_setprio(1);
            #pragma unroll
            for (int nt = 0; nt < 16; ++nt) {
                bf16x8 vf = *(const bf16x8*)&VT_lds[(nt * 16 + l16) * 64 + (((4 * c + quad) ^ sw) * 8)];
                o[nt] = __builtin_amdgcn_mfma_f32_16x16x32_bf16(pf, vf, o[nt], 0, 0, 0);
            }
            __builtin_amdgcn_s_setprio(0);
        }
    }

    l_run += __shfl_xor(l_run, 16);
    l_run += __shfl_xor(l_run, 32);
    float linv[4];
    #pragma unroll
    for (int r = 0; r < 4; ++r) linv[r] = 1.0f / __shfl(l_run, quad * 4 + r);

    // coalesced epilogue: O -> LDS (row-major 16x256, stride 264) -> dwordx4
    __syncthreads();
    unsigned short* W = SMEM + wave * (16 * 264);
    #pragma unroll
    for (int nt = 0; nt < 16; ++nt)
        #pragma unroll
        for (int r = 0; r < 4; ++r)
            W[(quad * 4 + r) * 264 + nt * 16 + l16] = f2bf(o[nt][r] * linv[r]);
    const int lr = lane >> 2, lc = (lane & 3) * 64;
    unsigned short* ob = out + (size_t)(b * T_SEQ + t0 + woff + lr) * 2048 + h * 256 + lc;
    #pragma unroll
    for (int j = 0; j < 8; ++j)
        *(uint4*)(ob + j * 8) = *(const uint4*)&W[lr * 264 + lc + j * 8];
}

// ------------------------------------------------------------- launch
extern "C" void kernel_launch(void* const* d_in, const int* in_sizes, int n_in,
                              void* d_out, int out_size, void* d_ws, size_t ws_size,
                              hipStream_t stream) {
    const void* x   = d_in[0];
    const int*  sp  = (const int*)d_in[1];
    const void* wq  = d_in[3];
    const void* wk  = d_in[4];
    const void* wv  = d_in[5];
    const void* wo  = d_in[6];
    const void* qsc = d_in[7];
    const void* ksc = d_in[8];

    unsigned short* ws = (unsigned short*)d_ws;
    int*            flag = (int*)ws;
    unsigned short* sbuf = ws + 1024;
    unsigned short* qkv  = (unsigned short*)d_out;
    dim3 blk(256);

    // Fused-QKV path needs: 2048 + xhat(8M) + wT(8M) ushorts = ~33.6 MB
    const size_t NEED = (size_t)(2048 + 8388608 + 8388608) * sizeof(unsigned short);

    detect_dtype<<<1, 64, 0, stream>>>((const unsigned short*)x, flag);

    if (ws_size >= NEED) {
        unsigned short* xhat = ws + 2048;                      // 4096x2048
        unsigned short* wT   = xhat + (size_t)4096 * 2048;     // 4096x2048 stacked
        unsigned short* abuf = xhat;                           // reuse after QKV
        unsigned short* vtb  = wT;                             // reuse after QKV GEMM
        unsigned short* woT  = wT + (size_t)2048 * 2048;       // after vt (4M us)

        convert_to_bf16<<<4096, blk, 0, stream>>>(x,   xhat,       flag, 4096 * 2048);
        convert_to_bf16<<<1,    blk, 0, stream>>>(qsc, sbuf,       flag, 256);
        convert_to_bf16<<<1,    blk, 0, stream>>>(ksc, sbuf + 256, flag, 256);

        // stacked B^T: rows 0..2047 = wq^T, 2048..3071 = wk^T, 3072..4095 = wv^T
        transpose_cvt<<<dim3(64, 64), blk, 0, stream>>>(wq, wT,                        flag, 2048, 2048);
        transpose_cvt<<<dim3(32, 64), blk, 0, stream>>>(wk, wT + (size_t)2048 * 2048,  flag, 2048, 1024);
        transpose_cvt<<<dim3(32, 64), blk, 0, stream>>>(wv, wT + (size_t)3072 * 2048,  flag, 2048, 1024);

        // single fused QKV GEMM: grid 32x32 = 1024 blocks (4/CU)
        gemm_bf16<<<dim3(32, 32), blk, 0, stream>>>(xhat, wT, qkv,
                                                    4096, 4096, 2048, 0, flag, 1);

        finalize_qk<<<12288, blk, 0, stream>>>(qkv, sp, sbuf);

        build_vt<<<dim3(64, 8, 8), blk, 0, stream>>>(qkv, vtb);
        attn_mfma<<<512, blk, 0, stream>>>(qkv, vtb, abuf);

        transpose_cvt<<<dim3(64, 64), blk, 0, stream>>>(wo, woT, flag, 2048, 2048);
        gemm_bf16<<<dim3(16, 32), blk, 0, stream>>>(abuf, woT, d_out,
                                                    4096, 2048, 2048, 0, flag, 0);
    } else {
        // fallback: previous (verified) two-GEMM layout, ~24.6 MB ws
        unsigned short* reg1 = ws + 2048;                      // 8,388,608 us
        unsigned short* reg2 = reg1 + (size_t)4096 * 2048;     // 4,194,304 us
        unsigned short* xhat = reg1;
        unsigned short* abuf = reg1;

        convert_to_bf16<<<4096, blk, 0, stream>>>(x,   xhat,       flag, 4096 * 2048);
        convert_to_bf16<<<1,    blk, 0, stream>>>(qsc, sbuf,       flag, 256);
        convert_to_bf16<<<1,    blk, 0, stream>>>(ksc, sbuf + 256, flag, 256);

        transpose_cvt<<<dim3(64, 64), blk, 0, stream>>>(wq, reg2, flag, 2048, 2048);
        gemm_bf16<<<dim3(16, 32), blk, 0, stream>>>(xhat, reg2, qkv,
                                                    4096, 4096, 2048, 0, flag, 1);
        transpose_cvt<<<dim3(32, 64), blk, 0, stream>>>(wk, reg2,                     flag, 2048, 1024);
        transpose_cvt<<<dim3(32, 64), blk, 0, stream>>>(wv, reg2 + (size_t)1024*2048, flag, 2048, 1024);
        gemm_bf16<<<dim3(16, 32), blk, 0, stream>>>(xhat, reg2, qkv,
                                                    4096, 4096, 2048, 2048, flag, 1);

        finalize_qk<<<12288, blk, 0, stream>>>(qkv, sp, sbuf);

        build_vt<<<dim3(64, 8, 8), blk, 0, stream>>>(qkv, reg2);
        attn_mfma<<<512, blk, 0, stream>>>(qkv, reg2, abuf);

        transpose_cvt<<<dim3(64, 64), blk, 0, stream>>>(wo, reg2, flag, 2048, 2048);
        gemm_bf16<<<dim3(16, 32), blk, 0, stream>>>(abuf, reg2, d_out,
                                                    4096, 2048, 2048, 0, flag, 0);
    }
}

// Round 3
// 380.655 us; speedup vs baseline: 1.2686x; 1.0523x over previous
//
#include <hip/hip_runtime.h>

#define T_SEQ 2048
#define NHEADS 8
#define NKV 4
#define HD 256
#define WIN 512

typedef __bf16 bf16x8 __attribute__((ext_vector_type(8)));
typedef float f32x4 __attribute__((ext_vector_type(4)));

__device__ __forceinline__ float bf2f(unsigned short u) {
    return __uint_as_float(((unsigned int)u) << 16);
}
__device__ __forceinline__ unsigned short f2bf(float f) {
    unsigned int u = __float_as_uint(f);
    u += 0x7fffu + ((u >> 16) & 1u);
    return (unsigned short)(u >> 16);
}

#define GLOAD_LDS16(gptr, lptr)                                            \
    __builtin_amdgcn_global_load_lds(                                      \
        (const __attribute__((address_space(1))) unsigned int*)(gptr),     \
        (__attribute__((address_space(3))) unsigned int*)(lptr), 16, 0, 0)

// ------------------------------------------------------------- dtype detect
__global__ void detect_dtype(const unsigned short* __restrict__ x, int* flag) {
    int tid = threadIdx.x;
    int cnt = 0;
    for (int i = 0; i < 64; ++i) {
        unsigned short u = x[2 * (tid * 64 + i)];
        int e = (u >> 7) & 0xFF;
        cnt += (e >= 100 && e <= 140) ? 1 : 0;
    }
    #pragma unroll
    for (int o = 32; o >= 1; o >>= 1) cnt += __shfl_xor(cnt, o);
    if (tid == 0) *flag = (cnt > 2048) ? 1 : 0;
}

// ------------------------------------------------------------- convert
__global__ __launch_bounds__(256) void convert_to_bf16(
    const void* __restrict__ src, unsigned short* __restrict__ dst,
    const int* __restrict__ flag, int n)
{
    int i = (blockIdx.x * 256 + threadIdx.x) * 8;
    if (i >= n) return;
    if (*flag) {
        *(uint4*)&dst[i] = *(const uint4*)((const unsigned short*)src + i);
    } else {
        const float* s = (const float*)src + i;
        unsigned short v[8];
        #pragma unroll
        for (int j = 0; j < 8; ++j) v[j] = f2bf(s[j]);
        *(uint4*)&dst[i] = *(uint4*)v;
    }
}

// ------------------------------------------------------------- transpose+cvt
__global__ __launch_bounds__(256) void transpose_cvt(
    const void* __restrict__ src, unsigned short* __restrict__ dst,
    const int* __restrict__ flag, int R, int C)
{
    __shared__ unsigned short tile[32][33];
    const int t = threadIdx.x;
    const int c = t & 31, r8 = t >> 5;
    const int bx = blockIdx.x, by = blockIdx.y;
    const int isb = *flag;
    #pragma unroll
    for (int i = 0; i < 4; ++i) {
        int r = r8 + i * 8;
        size_t idx = (size_t)(by * 32 + r) * C + bx * 32 + c;
        tile[r][c] = isb ? ((const unsigned short*)src)[idx]
                         : f2bf(((const float*)src)[idx]);
    }
    __syncthreads();
    #pragma unroll
    for (int i = 0; i < 4; ++i) {
        int r = r8 + i * 8;
        dst[(size_t)(bx * 32 + r) * R + by * 32 + c] = tile[c][r];
    }
}

// --------------------------------------------- fused wq/wk/wv transpose+cvt
// grid (128, 64): bx<64 -> wq (cols 2048), bx in [64,96) -> wk, [96,128) -> wv
// dst is stacked 4096x2048 B^T: rows 0..2047 wq^T, 2048..3071 wk^T, 3072.. wv^T
__global__ __launch_bounds__(256) void transpose_qkv_w(
    const void* __restrict__ wq, const void* __restrict__ wk,
    const void* __restrict__ wv, unsigned short* __restrict__ dst,
    const int* __restrict__ flag)
{
    __shared__ unsigned short tile[32][33];
    const int t = threadIdx.x;
    const int c = t & 31, r8 = t >> 5;
    const int bx = blockIdx.x, by = blockIdx.y;
    const void* src; int C, rowoff, cb;
    if (bx < 64)      { src = wq; C = 2048; rowoff = 0;    cb = bx; }
    else if (bx < 96) { src = wk; C = 1024; rowoff = 2048; cb = bx - 64; }
    else              { src = wv; C = 1024; rowoff = 3072; cb = bx - 96; }
    const int isb = *flag;
    #pragma unroll
    for (int i = 0; i < 4; ++i) {
        int r = r8 + i * 8;
        size_t idx = (size_t)(by * 32 + r) * C + cb * 32 + c;
        tile[r][c] = isb ? ((const unsigned short*)src)[idx]
                         : f2bf(((const float*)src)[idx]);
    }
    __syncthreads();
    #pragma unroll
    for (int i = 0; i < 4; ++i) {
        int r = r8 + i * 8;
        dst[(size_t)(rowoff + cb * 32 + r) * 2048 + by * 32 + c] = tile[c][r];
    }
}

// ------------------------------------------------------------- GEMM
// m97 tile/math + T3/T4: double-buffered LDS, 2-tile-deep global_load_lds
// prefetch, counted s_waitcnt vmcnt(4) + raw s_barrier (never vmcnt(0) in
// the main loop). Read/MFMA/epilogue identical to the verified kernel.
__global__ __launch_bounds__(256) void gemm_bf16(
    const unsigned short* __restrict__ A,
    const unsigned short* __restrict__ Bt,
    void* __restrict__ C,
    int M, int Ntot, int K, int n_base,
    const int* __restrict__ flag, int force_bf16)
{
    __shared__ __align__(16) unsigned short As[2][128 * 32];
    __shared__ __align__(16) unsigned short Bs[2][128 * 32];
    const int tid = threadIdx.x;
    const int n0 = blockIdx.x * 128;
    const int m0 = blockIdx.y * 128;
    const int wave = tid >> 6;
    const int lane = tid & 63;
    const int wm = (wave >> 1) * 64;
    const int wn = (wave & 1) * 64;
    const int quad = lane >> 4;
    const int l16 = lane & 15;
    const int obf = force_bf16 | *flag;

    // per-thread staging source pointers (2 chunks each for A and B)
    const int ch0 = tid, ch1 = tid + 256;
    const unsigned short* a0 = A  + (size_t)(m0 + (ch0 >> 2)) * K + (ch0 & 3) * 8;
    const unsigned short* a1 = A  + (size_t)(m0 + (ch1 >> 2)) * K + (ch1 & 3) * 8;
    const unsigned short* b0 = Bt + (size_t)(n0 + (ch0 >> 2)) * K + (ch0 & 3) * 8;
    const unsigned short* b1 = Bt + (size_t)(n0 + (ch1 >> 2)) * K + (ch1 & 3) * 8;

    f32x4 acc[4][4];
    #pragma unroll
    for (int i = 0; i < 4; ++i)
        #pragma unroll
        for (int j = 0; j < 4; ++j)
            acc[i][j] = f32x4{0.f, 0.f, 0.f, 0.f};

    const int NT = K >> 5;

#define STAGE_G(buf, tile_)                              \
    do { int _o = (tile_) * 32;                          \
        GLOAD_LDS16(a0 + _o, &As[buf][ch0 * 8]);         \
        GLOAD_LDS16(b0 + _o, &Bs[buf][ch0 * 8]);         \
        GLOAD_LDS16(a1 + _o, &As[buf][ch1 * 8]);         \
        GLOAD_LDS16(b1 + _o, &Bs[buf][ch1 * 8]);         \
    } while (0)

    STAGE_G(0, 0);
    STAGE_G(1, 1);

    for (int t = 0; t < NT; ++t) {
        // counted wait: tile t (4 loads) landed; tile t+1 may stay in flight
        if (t < NT - 1) asm volatile("s_waitcnt vmcnt(4)" ::: "memory");
        else            asm volatile("s_waitcnt vmcnt(0)" ::: "memory");
        __builtin_amdgcn_s_barrier();          // all waves' tile-t parts in LDS
        __builtin_amdgcn_sched_barrier(0);     // pin ds_reads below barrier

        const int cb = t & 1;
        bf16x8 af[4], bfr[4];
        #pragma unroll
        for (int mi = 0; mi < 4; ++mi)
            af[mi] = *(const bf16x8*)&As[cb][(wm + mi * 16 + l16) * 32 + quad * 8];
        #pragma unroll
        for (int ni = 0; ni < 4; ++ni)
            bfr[ni] = *(const bf16x8*)&Bs[cb][(wn + ni * 16 + l16) * 32 + quad * 8];
        #pragma unroll
        for (int mi = 0; mi < 4; ++mi)
            #pragma unroll
            for (int ni = 0; ni < 4; ++ni)
                acc[mi][ni] = __builtin_amdgcn_mfma_f32_16x16x32_bf16(
                    af[mi], bfr[ni], acc[mi][ni], 0, 0, 0);

        __builtin_amdgcn_sched_barrier(0);     // pin ds_reads above barrier
        __builtin_amdgcn_s_barrier();          // all waves done reading buf cb
        if (t + 2 < NT) STAGE_G(cb, t + 2);    // overwrite consumed buffer
    }
#undef STAGE_G

    #pragma unroll
    for (int mi = 0; mi < 4; ++mi)
        #pragma unroll
        for (int ni = 0; ni < 4; ++ni)
            #pragma unroll
            for (int r = 0; r < 4; ++r) {
                int row = m0 + wm + mi * 16 + quad * 4 + r;
                int col = n_base + n0 + wn + ni * 16 + l16;
                size_t idx = (size_t)row * Ntot + col;
                if (obf) ((unsigned short*)C)[idx] = f2bf(acc[mi][ni][r]);
                else     ((float*)C)[idx]          = acc[mi][ni][r];
            }
}

// ------------------------------------------------------------- finalize
// scales read directly from raw inputs (f32 or bf16 by flag) — the two
// 256-elem convert launches are gone.
__global__ __launch_bounds__(256) void finalize_qk(
    unsigned short* __restrict__ qkv,
    const int* __restrict__ segment_pos,
    const void* __restrict__ qs_raw,
    const void* __restrict__ ks_raw,
    const int* __restrict__ flag)
{
    const int w = blockIdx.x * 4 + (threadIdx.x >> 6);
    const int lane = threadIdx.x & 63;
    const int b = w / (T_SEQ * 12);
    const int rem = w % (T_SEQ * 12);
    const int t = rem / 12;
    const int slot = rem % 12;
    const bool isq = slot < 8;
    const int col0 = isq ? slot * 256 : 2048 + (slot - 8) * 256;
    unsigned short* p = qkv + (size_t)(b * T_SEQ + t) * 4096 + col0;
    const int isb = *flag;

    float e[4];
    #pragma unroll
    for (int j = 0; j < 4; ++j) e[j] = bf2f(p[lane + 64 * j]);
    float ss = e[0] * e[0] + e[1] * e[1] + e[2] * e[2] + e[3] * e[3];
    #pragma unroll
    for (int o = 32; o >= 1; o >>= 1) ss += __shfl_xor(ss, o);
    const float rn = rsqrtf(ss * (1.0f / 256.0f) + 1e-6f);
    const void* scp = isq ? qs_raw : ks_raw;
    float nrm[4];
    #pragma unroll
    for (int j = 0; j < 4; ++j) {
        float sc = isb ? bf2f(((const unsigned short*)scp)[lane + 64 * j])
                       : ((const float*)scp)[lane + 64 * j];
        nrm[j] = e[j] * rn * (1.0f + sc);
    }

    const int pos = segment_pos[b * T_SEQ + t];
    #pragma unroll
    for (int pp = 0; pp < 2; ++pp) {
        const int i = lane + 64 * pp;
        const float inv_ts = __expf((float)i * -0.07195578415606293f);
        float s, c;
        __sincosf((float)pos * inv_ts, &s, &c);
        const float x1 = nrm[pp], x2 = nrm[pp + 2];
        p[i]       = f2bf(x1 * c - x2 * s);
        p[i + 128] = f2bf(x2 * c + x1 * s);
    }
}

// ------------------------------------------------------------- V transpose
__global__ __launch_bounds__(256) void build_vt(
    const unsigned short* __restrict__ qkv, unsigned short* __restrict__ vt)
{
    __shared__ unsigned short tile[32][33];
    const int bkv = blockIdx.z;
    const int b = bkv >> 2, kv = bkv & 3;
    const int s0 = blockIdx.x * 32, d0 = blockIdx.y * 32;
    const int c = threadIdx.x & 31, r8 = threadIdx.x >> 5;
    #pragma unroll
    for (int i = 0; i < 4; ++i) {
        int r = r8 + i * 8;
        tile[r][c] = qkv[(size_t)(b * T_SEQ + s0 + r) * 4096 + 3072 + kv * 256 + d0 + c];
    }
    __syncthreads();
    #pragma unroll
    for (int i = 0; i < 4; ++i) {
        int r = r8 + i * 8;
        vt[((size_t)bkv * 256 + d0 + r) * T_SEQ + s0 + c] = tile[c][r];
    }
}

// ------------------------------------------------------------- MFMA attention
#define PSTR 80
__global__ __launch_bounds__(256, 2) void attn_mfma(
    const unsigned short* __restrict__ qkv,
    const unsigned short* __restrict__ vt,
    unsigned short* __restrict__ out)
{
    __shared__ __align__(16) unsigned short SMEM[16384 + 16384 + 4 * 16 * PSTR];
    unsigned short* K_lds  = SMEM;            // 64 x 256 (swizzled)
    unsigned short* VT_lds = SMEM + 16384;    // 256 x 64 (swizzled)

    const int tid = threadIdx.x;
    const int wave = tid >> 6, lane = tid & 63;
    const int l16 = lane & 15, quad = lane >> 4;
    const int sw = l16 & 7;
    const int bkv = blockIdx.x & 7;           // XCD swizzle: same bkv -> same XCD
    const int qt  = blockIdx.x >> 3;
    const int b = bkv >> 2, kvh = bkv & 3;
    const int t0 = qt * 32;
    const int h = kvh * 2 + (wave >> 1);
    const int woff = (wave & 1) * 16;
    const int tq = t0 + woff + l16;
    unsigned short* P_lds = SMEM + 32768 + wave * 16 * PSTR;

    bf16x8 qf[8];
    {
        const unsigned short* qp =
            qkv + (size_t)(b * T_SEQ + tq) * 4096 + h * 256 + quad * 8;
        #pragma unroll
        for (int c = 0; c < 8; ++c) qf[c] = *(const bf16x8*)(qp + 32 * c);
    }

    f32x4 o[16];
    #pragma unroll
    for (int nt = 0; nt < 16; ++nt) o[nt] = f32x4{0.f, 0.f, 0.f, 0.f};
    float l_run = 0.f;

    int s_lo = t0 - (WIN - 1); if (s_lo < 0) s_lo = 0;
    const int s_base = s_lo & ~63;
    const int s_last = t0 + 31;
    const int tqmin = t0 + woff;
    const int tqmax = tqmin + 15;
    const int wlo   = tqmin - (WIN - 1);      // lowest key this wave can see
    const size_t kgbase = (size_t)b * T_SEQ * 4096 + 2048 + kvh * 256;
    const size_t vgbase = (size_t)bkv * 256 * T_SEQ;

    for (int sb = s_base; sb <= s_last; sb += 64) {
        __syncthreads();   // previous tile fully consumed

        // K tile: linear LDS dest, source column pre-swizzled (m173 pattern)
        #pragma unroll
        for (int i = 0; i < 8; ++i) {
            int ch = tid + 256 * i;
            int row = ch >> 5, e8 = ch & 31;
            GLOAD_LDS16(&qkv[kgbase + (size_t)(sb + row) * 4096
                             + ((e8 ^ (row & 7)) * 8)],
                        &K_lds[ch * 8]);
        }
        // VT tile
        #pragma unroll
        for (int i = 0; i < 8; ++i) {
            int ch = tid + 256 * i;
            int dr = ch >> 3, e8 = ch & 7;
            GLOAD_LDS16(&vt[vgbase + (size_t)dr * T_SEQ + sb
                            + ((e8 ^ (dr & 7)) * 8)],
                        &VT_lds[ch * 8]);
        }
        __syncthreads();   // drains vmcnt(0): tile resident in LDS

        if (sb > tqmax || sb + 63 < wlo) continue;   // wave-uniform skip

        // S^T = K · Q^T
        f32x4 st[4];
        #pragma unroll
        for (int mt = 0; mt < 4; ++mt) st[mt] = f32x4{0.f, 0.f, 0.f, 0.f};
        __builtin_amdgcn_s_setprio(1);
        #pragma unroll
        for (int c = 0; c < 8; ++c) {
            bf16x8 kf[4];
            #pragma unroll
            for (int mt = 0; mt < 4; ++mt)
                kf[mt] = *(const bf16x8*)&K_lds[(mt * 16 + l16) * 256 + (((4 * c + quad) ^ sw) * 8)];
            #pragma unroll
            for (int mt = 0; mt < 4; ++mt)
                st[mt] = __builtin_amdgcn_mfma_f32_16x16x32_bf16(kf[mt], qf[c], st[mt], 0, 0, 0);
        }
        __builtin_amdgcn_s_setprio(0);

        // softcap + exp(static m=30); P -> LDS
        #pragma unroll
        for (int mt = 0; mt < 4; ++mt)
            #pragma unroll
            for (int r = 0; r < 4; ++r) {
                int sp = sb + mt * 16 + quad * 4 + r;
                float e2 = __expf(st[mt][r] * 0.0025f);         // exp(2*logits/800)
                float p = __expf(20.0f - 100.0f / (e2 + 1.0f)); // exp(softcap - 30)
                bool valid = (sp <= tq) && (tq - sp < WIN);
                p = valid ? p : 0.0f;
                l_run += p;
                P_lds[l16 * PSTR + mt * 16 + quad * 4 + r] = f2bf(p);
            }

        // O += P · V^T
        #pragma unroll
        for (int c = 0; c < 2; ++c) {
            bf16x8 pf = *(const bf16x8*)&P_lds[l16 * PSTR + 32 * c + quad * 8];
            __builtin_amdgcn_s_setprio(1);
            #pragma unroll
            for (int nt = 0; nt < 16; ++nt) {
                bf16x8 vf = *(const bf16x8*)&VT_lds[(nt * 16 + l16) * 64 + (((4 * c + quad) ^ sw) * 8)];
                o[nt] = __builtin_amdgcn_mfma_f32_16x16x32_bf16(pf, vf, o[nt], 0, 0, 0);
            }
            __builtin_amdgcn_s_setprio(0);
        }
    }

    l_run += __shfl_xor(l_run, 16);
    l_run += __shfl_xor(l_run, 32);
    float linv[4];
    #pragma unroll
    for (int r = 0; r < 4; ++r) linv[r] = 1.0f / __shfl(l_run, quad * 4 + r);

    // coalesced epilogue: O -> LDS (row-major 16x256, stride 264) -> dwordx4
    __syncthreads();
    unsigned short* W = SMEM + wave * (16 * 264);
    #pragma unroll
    for (int nt = 0; nt < 16; ++nt)
        #pragma unroll
        for (int r = 0; r < 4; ++r)
            W[(quad * 4 + r) * 264 + nt * 16 + l16] = f2bf(o[nt][r] * linv[r]);
    const int lr = lane >> 2, lc = (lane & 3) * 64;
    unsigned short* ob = out + (size_t)(b * T_SEQ + t0 + woff + lr) * 2048 + h * 256 + lc;
    #pragma unroll
    for (int j = 0; j < 8; ++j)
        *(uint4*)(ob + j * 8) = *(const uint4*)&W[lr * 264 + lc + j * 8];
}

// ------------------------------------------------------------- launch
extern "C" void kernel_launch(void* const* d_in, const int* in_sizes, int n_in,
                              void* d_out, int out_size, void* d_ws, size_t ws_size,
                              hipStream_t stream) {
    const void* x   = d_in[0];
    const int*  sp  = (const int*)d_in[1];
    const void* wq  = d_in[3];
    const void* wk  = d_in[4];
    const void* wv  = d_in[5];
    const void* wo  = d_in[6];
    const void* qsc = d_in[7];
    const void* ksc = d_in[8];

    unsigned short* ws = (unsigned short*)d_ws;
    int*            flag = (int*)ws;
    unsigned short* qkv  = (unsigned short*)d_out;
    dim3 blk(256);

    // Fused-QKV path needs: 2048 + xhat(8M) + wT(8M) ushorts = ~33.6 MB
    const size_t NEED = (size_t)(2048 + 8388608 + 8388608) * sizeof(unsigned short);

    detect_dtype<<<1, 64, 0, stream>>>((const unsigned short*)x, flag);

    if (ws_size >= NEED) {
        unsigned short* xhat = ws + 2048;                      // 4096x2048
        unsigned short* wT   = xhat + (size_t)4096 * 2048;     // 4096x2048 stacked
        unsigned short* abuf = xhat;                           // reuse after QKV
        unsigned short* vtb  = wT;                             // reuse after QKV GEMM
        unsigned short* woT  = wT + (size_t)2048 * 2048;       // after vt (4M us)

        convert_to_bf16<<<4096, blk, 0, stream>>>(x, xhat, flag, 4096 * 2048);

        // stacked B^T: one fused transpose for wq/wk/wv
        transpose_qkv_w<<<dim3(128, 64), blk, 0, stream>>>(wq, wk, wv, wT, flag);

        // single fused QKV GEMM: grid 32x32 = 1024 blocks
        gemm_bf16<<<dim3(32, 32), blk, 0, stream>>>(xhat, wT, qkv,
                                                    4096, 4096, 2048, 0, flag, 1);

        finalize_qk<<<12288, blk, 0, stream>>>(qkv, sp, qsc, ksc, flag);

        build_vt<<<dim3(64, 8, 8), blk, 0, stream>>>(qkv, vtb);
        attn_mfma<<<512, blk, 0, stream>>>(qkv, vtb, abuf);

        transpose_cvt<<<dim3(64, 64), blk, 0, stream>>>(wo, woT, flag, 2048, 2048);
        gemm_bf16<<<dim3(16, 32), blk, 0, stream>>>(abuf, woT, d_out,
                                                    4096, 2048, 2048, 0, flag, 0);
    } else {
        // fallback: two-GEMM layout, ~24.6 MB ws
        unsigned short* reg1 = ws + 2048;                      // 8,388,608 us
        unsigned short* reg2 = reg1 + (size_t)4096 * 2048;     // 4,194,304 us
        unsigned short* xhat = reg1;
        unsigned short* abuf = reg1;

        convert_to_bf16<<<4096, blk, 0, stream>>>(x, xhat, flag, 4096 * 2048);

        transpose_cvt<<<dim3(64, 64), blk, 0, stream>>>(wq, reg2, flag, 2048, 2048);
        gemm_bf16<<<dim3(16, 32), blk, 0, stream>>>(xhat, reg2, qkv,
                                                    4096, 4096, 2048, 0, flag, 1);
        transpose_cvt<<<dim3(32, 64), blk, 0, stream>>>(wk, reg2,                     flag, 2048, 1024);
        transpose_cvt<<<dim3(32, 64), blk, 0, stream>>>(wv, reg2 + (size_t)1024*2048, flag, 2048, 1024);
        gemm_bf16<<<dim3(16, 32), blk, 0, stream>>>(xhat, reg2, qkv,
                                                    4096, 4096, 2048, 2048, flag, 1);

        finalize_qk<<<12288, blk, 0, stream>>>(qkv, sp, qsc, ksc, flag);

        build_vt<<<dim3(64, 8, 8), blk, 0, stream>>>(qkv, reg2);
        attn_mfma<<<512, blk, 0, stream>>>(qkv, reg2, abuf);

        transpose_cvt<<<dim3(64, 64), blk, 0, stream>>>(wo, reg2, flag, 2048, 2048);
        gemm_bf16<<<dim3(16, 32), blk, 0, stream>>>(abuf, reg2, d_out,
                                                    4096, 2048, 2048, 0, flag, 0);
    }
}

// Round 4
// 362.087 us; speedup vs baseline: 1.3336x; 1.0513x over previous
//
#include <hip/hip_runtime.h>

#define T_SEQ 2048
#define NHEADS 8
#define NKV 4
#define HD 256
#define WIN 512

typedef __bf16 bf16x8 __attribute__((ext_vector_type(8)));
typedef float f32x4 __attribute__((ext_vector_type(4)));

__device__ __forceinline__ float bf2f(unsigned short u) {
    return __uint_as_float(((unsigned int)u) << 16);
}
__device__ __forceinline__ unsigned short f2bf(float f) {
    unsigned int u = __float_as_uint(f);
    u += 0x7fffu + ((u >> 16) & 1u);
    return (unsigned short)(u >> 16);
}

#define GLOAD_LDS16(gptr, lptr)                                            \
    __builtin_amdgcn_global_load_lds(                                      \
        (const __attribute__((address_space(1))) unsigned int*)(gptr),     \
        (__attribute__((address_space(3))) unsigned int*)(lptr), 16, 0, 0)

// ------------------------------------------------------------- dtype detect
__global__ void detect_dtype(const unsigned short* __restrict__ x, int* flag) {
    int tid = threadIdx.x;
    int cnt = 0;
    for (int i = 0; i < 64; ++i) {
        unsigned short u = x[2 * (tid * 64 + i)];
        int e = (u >> 7) & 0xFF;
        cnt += (e >= 100 && e <= 140) ? 1 : 0;
    }
    #pragma unroll
    for (int o = 32; o >= 1; o >>= 1) cnt += __shfl_xor(cnt, o);
    if (tid == 0) *flag = (cnt > 2048) ? 1 : 0;
}

// ------------------------------------------------------------- convert
__global__ __launch_bounds__(256) void convert_to_bf16(
    const void* __restrict__ src, unsigned short* __restrict__ dst,
    const int* __restrict__ flag, int n)
{
    int i = (blockIdx.x * 256 + threadIdx.x) * 8;
    if (i >= n) return;
    if (*flag) {
        *(uint4*)&dst[i] = *(const uint4*)((const unsigned short*)src + i);
    } else {
        const float* s = (const float*)src + i;
        unsigned short v[8];
        #pragma unroll
        for (int j = 0; j < 8; ++j) v[j] = f2bf(s[j]);
        *(uint4*)&dst[i] = *(uint4*)v;
    }
}

// ------------------------------------------------------------- transpose+cvt
__global__ __launch_bounds__(256) void transpose_cvt(
    const void* __restrict__ src, unsigned short* __restrict__ dst,
    const int* __restrict__ flag, int R, int C)
{
    __shared__ unsigned short tile[32][33];
    const int t = threadIdx.x;
    const int c = t & 31, r8 = t >> 5;
    const int bx = blockIdx.x, by = blockIdx.y;
    const int isb = *flag;
    #pragma unroll
    for (int i = 0; i < 4; ++i) {
        int r = r8 + i * 8;
        size_t idx = (size_t)(by * 32 + r) * C + bx * 32 + c;
        tile[r][c] = isb ? ((const unsigned short*)src)[idx]
                         : f2bf(((const float*)src)[idx]);
    }
    __syncthreads();
    #pragma unroll
    for (int i = 0; i < 4; ++i) {
        int r = r8 + i * 8;
        dst[(size_t)(bx * 32 + r) * R + by * 32 + c] = tile[c][r];
    }
}

// --------------------------------------------- fused wq/wk/wv transpose+cvt
__global__ __launch_bounds__(256) void transpose_qkv_w(
    const void* __restrict__ wq, const void* __restrict__ wk,
    const void* __restrict__ wv, unsigned short* __restrict__ dst,
    const int* __restrict__ flag)
{
    __shared__ unsigned short tile[32][33];
    const int t = threadIdx.x;
    const int c = t & 31, r8 = t >> 5;
    const int bx = blockIdx.x, by = blockIdx.y;
    const void* src; int C, rowoff, cb;
    if (bx < 64)      { src = wq; C = 2048; rowoff = 0;    cb = bx; }
    else if (bx < 96) { src = wk; C = 1024; rowoff = 2048; cb = bx - 64; }
    else              { src = wv; C = 1024; rowoff = 3072; cb = bx - 96; }
    const int isb = *flag;
    #pragma unroll
    for (int i = 0; i < 4; ++i) {
        int r = r8 + i * 8;
        size_t idx = (size_t)(by * 32 + r) * C + cb * 32 + c;
        tile[r][c] = isb ? ((const unsigned short*)src)[idx]
                         : f2bf(((const float*)src)[idx]);
    }
    __syncthreads();
    #pragma unroll
    for (int i = 0; i < 4; ++i) {
        int r = r8 + i * 8;
        dst[(size_t)(rowoff + cb * 32 + r) * 2048 + by * 32 + c] = tile[c][r];
    }
}

// ------------------------------------------------------------- GEMM 128 (m97)
// kept for the wo projection (N=2048 -> 512 blocks keeps all CUs busy)
__global__ __launch_bounds__(256) void gemm_bf16(
    const unsigned short* __restrict__ A,
    const unsigned short* __restrict__ Bt,
    void* __restrict__ C,
    int M, int Ntot, int K, int n_base,
    const int* __restrict__ flag, int force_bf16)
{
    __shared__ __align__(16) unsigned short As[128 * 32];
    __shared__ __align__(16) unsigned short Bs[128 * 32];
    const int tid = threadIdx.x;
    const int n0 = blockIdx.x * 128;
    const int m0 = blockIdx.y * 128;
    const int wave = tid >> 6;
    const int lane = tid & 63;
    const int wm = (wave >> 1) * 64;
    const int wn = (wave & 1) * 64;
    const int quad = lane >> 4;
    const int l16 = lane & 15;
    const int obf = force_bf16 | *flag;

    f32x4 acc[4][4];
    #pragma unroll
    for (int i = 0; i < 4; ++i)
        #pragma unroll
        for (int j = 0; j < 4; ++j)
            acc[i][j] = f32x4{0.f, 0.f, 0.f, 0.f};

    for (int kk = 0; kk < K; kk += 32) {
        #pragma unroll
        for (int i = 0; i < 2; ++i) {
            int ch = tid + i * 256;
            int row = ch >> 2;
            int ko = (ch & 3) * 8;
            GLOAD_LDS16(&A[(size_t)(m0 + row) * K + kk + ko],  &As[ch * 8]);
            GLOAD_LDS16(&Bt[(size_t)(n0 + row) * K + kk + ko], &Bs[ch * 8]);
        }
        __syncthreads();
        bf16x8 af[4], bfr[4];
        #pragma unroll
        for (int mi = 0; mi < 4; ++mi)
            af[mi] = *(const bf16x8*)&As[(wm + mi * 16 + l16) * 32 + quad * 8];
        #pragma unroll
        for (int ni = 0; ni < 4; ++ni)
            bfr[ni] = *(const bf16x8*)&Bs[(wn + ni * 16 + l16) * 32 + quad * 8];
        #pragma unroll
        for (int mi = 0; mi < 4; ++mi)
            #pragma unroll
            for (int ni = 0; ni < 4; ++ni)
                acc[mi][ni] = __builtin_amdgcn_mfma_f32_16x16x32_bf16(
                    af[mi], bfr[ni], acc[mi][ni], 0, 0, 0);
        __syncthreads();
    }

    #pragma unroll
    for (int mi = 0; mi < 4; ++mi)
        #pragma unroll
        for (int ni = 0; ni < 4; ++ni)
            #pragma unroll
            for (int r = 0; r < 4; ++r) {
                int row = m0 + wm + mi * 16 + quad * 4 + r;
                int col = n_base + n0 + wn + ni * 16 + l16;
                size_t idx = (size_t)row * Ntot + col;
                if (obf) ((unsigned short*)C)[idx] = f2bf(acc[mi][ni][r]);
                else     ((float*)C)[idx]          = acc[mi][ni][r];
            }
}

// ------------------------------------------------------------- GEMM 256
// 256x256 tile, BK=64, 8 waves (2M x 4N), 128 KiB dbuf LDS, XOR-swizzled
// (linear DMA dest + pre-swizzled global source + swizzled ds_read, rule 21).
// Stage-early global_load_lds; single __syncthreads per K-tile (its implicit
// vmcnt(0) drain is amortized over ~2000 cyc of MFMA); T5 setprio clusters.
__global__ __launch_bounds__(512, 2) void gemm256_bf16(
    const unsigned short* __restrict__ A,
    const unsigned short* __restrict__ Bt,
    void* __restrict__ C,
    int M, int Ntot, int K, int n_base, int gx,
    const int* __restrict__ flag, int force_bf16)
{
    __shared__ __align__(16) unsigned short A_lds[2][256 * 64];
    __shared__ __align__(16) unsigned short B_lds[2][256 * 64];

    const int tid = threadIdx.x;
    // T1: bijective XCD swizzle (gridDim.x % 8 == 0)
    const int cpx = gridDim.x >> 3;
    const int swzb = (blockIdx.x & 7) * cpx + (blockIdx.x >> 3);
    const int bx = swzb % gx, by = swzb / gx;
    const int n0 = bx * 256, m0 = by * 256;

    const int wave = tid >> 6, lane = tid & 63;
    const int wr = wave >> 2, wc = wave & 3;          // 2M x 4N
    const int quad = lane >> 4, l16 = lane & 15;
    const int sw7 = l16 & 7;
    const int obf = force_bf16 | *flag;

    // staging: thread handles chunks c = tid + 512j; row = c>>3, cpos = c&7
    // LDS content at (row, cpos) = M[row][(cpos ^ (row&7))*8 ..]  (involution)
    const int r0 = tid >> 3;                              // 0..63
    const int chs = ((tid & 7) ^ (r0 & 7)) * 8;           // pre-swizzled col
    const unsigned short* Ab = A  + (size_t)(m0 + r0) * K + chs;
    const unsigned short* Bb = Bt + (size_t)(n0 + r0) * K + chs;

    f32x4 acc[8][4];
    #pragma unroll
    for (int i = 0; i < 8; ++i)
        #pragma unroll
        for (int j = 0; j < 4; ++j)
            acc[i][j] = f32x4{0.f, 0.f, 0.f, 0.f};

    const int NT = K >> 6;

#define STAGE256(buf_, kt_)                                               \
    do {                                                                  \
        _Pragma("unroll")                                                 \
        for (int j = 0; j < 4; ++j) {                                     \
            GLOAD_LDS16(Ab + (size_t)(64 * j) * K + (kt_) * 64,           \
                        &A_lds[buf_][(tid + 512 * j) * 8]);               \
            GLOAD_LDS16(Bb + (size_t)(64 * j) * K + (kt_) * 64,           \
                        &B_lds[buf_][(tid + 512 * j) * 8]);               \
        }                                                                 \
    } while (0)

    STAGE256(0, 0);
    __syncthreads();                       // drains vmcnt(0): tile0 resident

    for (int t = 0; t < NT; ++t) {
        const int cb = t & 1;
        if (t + 1 < NT) STAGE256(cb ^ 1, t + 1);   // stage-early, lands during compute

        const unsigned short* Ac = A_lds[cb];
        const unsigned short* Bc = B_lds[cb];
        bf16x8 a4[4][2], b2[2][2];

        // ---- SP0: A mi0-3 + B ni0-1, MFMA quadrant (0-3, 0-1)
        #pragma unroll
        for (int mi = 0; mi < 4; ++mi)
            #pragma unroll
            for (int ks = 0; ks < 2; ++ks)
                a4[mi][ks] = *(const bf16x8*)&Ac[(wr * 128 + mi * 16 + l16) * 64
                                                + (((ks * 4 + quad) ^ sw7) * 8)];
        #pragma unroll
        for (int ni = 0; ni < 2; ++ni)
            #pragma unroll
            for (int ks = 0; ks < 2; ++ks)
                b2[ni][ks] = *(const bf16x8*)&Bc[(wc * 64 + ni * 16 + l16) * 64
                                                + (((ks * 4 + quad) ^ sw7) * 8)];
        __builtin_amdgcn_s_setprio(1);
        #pragma unroll
        for (int mi = 0; mi < 4; ++mi)
            #pragma unroll
            for (int ni = 0; ni < 2; ++ni)
                #pragma unroll
                for (int ks = 0; ks < 2; ++ks)
                    acc[mi][ni] = __builtin_amdgcn_mfma_f32_16x16x32_bf16(
                        a4[mi][ks], b2[ni][ks], acc[mi][ni], 0, 0, 0);
        __builtin_amdgcn_s_setprio(0);

        // ---- SP1: B ni2-3 (A reused), MFMA quadrant (0-3, 2-3)
        #pragma unroll
        for (int ni = 0; ni < 2; ++ni)
            #pragma unroll
            for (int ks = 0; ks < 2; ++ks)
                b2[ni][ks] = *(const bf16x8*)&Bc[(wc * 64 + (ni + 2) * 16 + l16) * 64
                                                + (((ks * 4 + quad) ^ sw7) * 8)];
        __builtin_amdgcn_s_setprio(1);
        #pragma unroll
        for (int mi = 0; mi < 4; ++mi)
            #pragma unroll
            for (int ni = 0; ni < 2; ++ni)
                #pragma unroll
                for (int ks = 0; ks < 2; ++ks)
                    acc[mi][ni + 2] = __builtin_amdgcn_mfma_f32_16x16x32_bf16(
                        a4[mi][ks], b2[ni][ks], acc[mi][ni + 2], 0, 0, 0);
        __builtin_amdgcn_s_setprio(0);

        // ---- SP2: A mi4-7 + B ni0-1, MFMA quadrant (4-7, 0-1)
        #pragma unroll
        for (int mi = 0; mi < 4; ++mi)
            #pragma unroll
            for (int ks = 0; ks < 2; ++ks)
                a4[mi][ks] = *(const bf16x8*)&Ac[(wr * 128 + (mi + 4) * 16 + l16) * 64
                                                + (((ks * 4 + quad) ^ sw7) * 8)];
        #pragma unroll
        for (int ni = 0; ni < 2; ++ni)
            #pragma unroll
            for (int ks = 0; ks < 2; ++ks)
                b2[ni][ks] = *(const bf16x8*)&Bc[(wc * 64 + ni * 16 + l16) * 64
                                                + (((ks * 4 + quad) ^ sw7) * 8)];
        __builtin_amdgcn_s_setprio(1);
        #pragma unroll
        for (int mi = 0; mi < 4; ++mi)
            #pragma unroll
            for (int ni = 0; ni < 2; ++ni)
                #pragma unroll
                for (int ks = 0; ks < 2; ++ks)
                    acc[mi + 4][ni] = __builtin_amdgcn_mfma_f32_16x16x32_bf16(
                        a4[mi][ks], b2[ni][ks], acc[mi + 4][ni], 0, 0, 0);
        __builtin_amdgcn_s_setprio(0);

        // ---- SP3: B ni2-3 (A reused), MFMA quadrant (4-7, 2-3)
        #pragma unroll
        for (int ni = 0; ni < 2; ++ni)
            #pragma unroll
            for (int ks = 0; ks < 2; ++ks)
                b2[ni][ks] = *(const bf16x8*)&Bc[(wc * 64 + (ni + 2) * 16 + l16) * 64
                                                + (((ks * 4 + quad) ^ sw7) * 8)];
        __builtin_amdgcn_s_setprio(1);
        #pragma unroll
        for (int mi = 0; mi < 4; ++mi)
            #pragma unroll
            for (int ni = 0; ni < 2; ++ni)
                #pragma unroll
                for (int ks = 0; ks < 2; ++ks)
                    acc[mi + 4][ni + 2] = __builtin_amdgcn_mfma_f32_16x16x32_bf16(
                        a4[mi][ks], b2[ni][ks], acc[mi + 4][ni + 2], 0, 0, 0);
        __builtin_amdgcn_s_setprio(0);

        __syncthreads();   // implicit vmcnt(0)+lgkmcnt(0): t+1 resident, tile t closed
    }
#undef STAGE256

    #pragma unroll
    for (int mi = 0; mi < 8; ++mi)
        #pragma unroll
        for (int ni = 0; ni < 4; ++ni)
            #pragma unroll
            for (int r = 0; r < 4; ++r) {
                int row = m0 + wr * 128 + mi * 16 + quad * 4 + r;
                int col = n_base + n0 + wc * 64 + ni * 16 + l16;
                size_t idx = (size_t)row * Ntot + col;
                if (obf) ((unsigned short*)C)[idx] = f2bf(acc[mi][ni][r]);
                else     ((float*)C)[idx]          = acc[mi][ni][r];
            }
}

// ------------------------------------------------------------- finalize
__global__ __launch_bounds__(256) void finalize_qk(
    unsigned short* __restrict__ qkv,
    const int* __restrict__ segment_pos,
    const void* __restrict__ qs_raw,
    const void* __restrict__ ks_raw,
    const int* __restrict__ flag)
{
    const int w = blockIdx.x * 4 + (threadIdx.x >> 6);
    const int lane = threadIdx.x & 63;
    const int b = w / (T_SEQ * 12);
    const int rem = w % (T_SEQ * 12);
    const int t = rem / 12;
    const int slot = rem % 12;
    const bool isq = slot < 8;
    const int col0 = isq ? slot * 256 : 2048 + (slot - 8) * 256;
    unsigned short* p = qkv + (size_t)(b * T_SEQ + t) * 4096 + col0;
    const int isb = *flag;

    float e[4];
    #pragma unroll
    for (int j = 0; j < 4; ++j) e[j] = bf2f(p[lane + 64 * j]);
    float ss = e[0] * e[0] + e[1] * e[1] + e[2] * e[2] + e[3] * e[3];
    #pragma unroll
    for (int o = 32; o >= 1; o >>= 1) ss += __shfl_xor(ss, o);
    const float rn = rsqrtf(ss * (1.0f / 256.0f) + 1e-6f);
    const void* scp = isq ? qs_raw : ks_raw;
    float nrm[4];
    #pragma unroll
    for (int j = 0; j < 4; ++j) {
        float sc = isb ? bf2f(((const unsigned short*)scp)[lane + 64 * j])
                       : ((const float*)scp)[lane + 64 * j];
        nrm[j] = e[j] * rn * (1.0f + sc);
    }

    const int pos = segment_pos[b * T_SEQ + t];
    #pragma unroll
    for (int pp = 0; pp < 2; ++pp) {
        const int i = lane + 64 * pp;
        const float inv_ts = __expf((float)i * -0.07195578415606293f);
        float s, c;
        __sincosf((float)pos * inv_ts, &s, &c);
        const float x1 = nrm[pp], x2 = nrm[pp + 2];
        p[i]       = f2bf(x1 * c - x2 * s);
        p[i + 128] = f2bf(x2 * c + x1 * s);
    }
}

// ------------------------------------------------------------- V transpose
__global__ __launch_bounds__(256) void build_vt(
    const unsigned short* __restrict__ qkv, unsigned short* __restrict__ vt)
{
    __shared__ unsigned short tile[32][33];
    const int bkv = blockIdx.z;
    const int b = bkv >> 2, kv = bkv & 3;
    const int s0 = blockIdx.x * 32, d0 = blockIdx.y * 32;
    const int c = threadIdx.x & 31, r8 = threadIdx.x >> 5;
    #pragma unroll
    for (int i = 0; i < 4; ++i) {
        int r = r8 + i * 8;
        tile[r][c] = qkv[(size_t)(b * T_SEQ + s0 + r) * 4096 + 3072 + kv * 256 + d0 + c];
    }
    __syncthreads();
    #pragma unroll
    for (int i = 0; i < 4; ++i) {
        int r = r8 + i * 8;
        vt[((size_t)bkv * 256 + d0 + r) * T_SEQ + s0 + c] = tile[c][r];
    }
}

// ------------------------------------------------------------- MFMA attention
#define PSTR 80
__global__ __launch_bounds__(256, 2) void attn_mfma(
    const unsigned short* __restrict__ qkv,
    const unsigned short* __restrict__ vt,
    unsigned short* __restrict__ out)
{
    __shared__ __align__(16) unsigned short SMEM[16384 + 16384 + 4 * 16 * PSTR];
    unsigned short* K_lds  = SMEM;            // 64 x 256 (swizzled)
    unsigned short* VT_lds = SMEM + 16384;    // 256 x 64 (swizzled)

    const int tid = threadIdx.x;
    const int wave = tid >> 6, lane = tid & 63;
    const int l16 = lane & 15, quad = lane >> 4;
    const int sw = l16 & 7;
    const int bkv = blockIdx.x & 7;           // XCD swizzle: same bkv -> same XCD
    const int qt  = blockIdx.x >> 3;
    const int b = bkv >> 2, kvh = bkv & 3;
    const int t0 = qt * 32;
    const int h = kvh * 2 + (wave >> 1);
    const int woff = (wave & 1) * 16;
    const int tq = t0 + woff + l16;
    unsigned short* P_lds = SMEM + 32768 + wave * 16 * PSTR;

    bf16x8 qf[8];
    {
        const unsigned short* qp =
            qkv + (size_t)(b * T_SEQ + tq) * 4096 + h * 256 + quad * 8;
        #pragma unroll
        for (int c = 0; c < 8; ++c) qf[c] = *(const bf16x8*)(qp + 32 * c);
    }

    f32x4 o[16];
    #pragma unroll
    for (int nt = 0; nt < 16; ++nt) o[nt] = f32x4{0.f, 0.f, 0.f, 0.f};
    float l_run = 0.f;

    int s_lo = t0 - (WIN - 1); if (s_lo < 0) s_lo = 0;
    const int s_base = s_lo & ~63;
    const int s_last = t0 + 31;
    const int tqmin = t0 + woff;
    const int tqmax = tqmin + 15;
    const int wlo   = tqmin - (WIN - 1);      // lowest key this wave can see
    const size_t kgbase = (size_t)b * T_SEQ * 4096 + 2048 + kvh * 256;
    const size_t vgbase = (size_t)bkv * 256 * T_SEQ;

    for (int sb = s_base; sb <= s_last; sb += 64) {
        __syncthreads();   // previous tile fully consumed

        // K tile: linear LDS dest, source column pre-swizzled (m173 pattern)
        #pragma unroll
        for (int i = 0; i < 8; ++i) {
            int ch = tid + 256 * i;
            int row = ch >> 5, e8 = ch & 31;
            GLOAD_LDS16(&qkv[kgbase + (size_t)(sb + row) * 4096
                             + ((e8 ^ (row & 7)) * 8)],
                        &K_lds[ch * 8]);
        }
        // VT tile
        #pragma unroll
        for (int i = 0; i < 8; ++i) {
            int ch = tid + 256 * i;
            int dr = ch >> 3, e8 = ch & 7;
            GLOAD_LDS16(&vt[vgbase + (size_t)dr * T_SEQ + sb
                            + ((e8 ^ (dr & 7)) * 8)],
                        &VT_lds[ch * 8]);
        }
        __syncthreads();   // drains vmcnt(0): tile resident in LDS

        if (sb > tqmax || sb + 63 < wlo) continue;   // wave-uniform skip

        // S^T = K · Q^T
        f32x4 st[4];
        #pragma unroll
        for (int mt = 0; mt < 4; ++mt) st[mt] = f32x4{0.f, 0.f, 0.f, 0.f};
        __builtin_amdgcn_s_setprio(1);
        #pragma unroll
        for (int c = 0; c < 8; ++c) {
            bf16x8 kf[4];
            #pragma unroll
            for (int mt = 0; mt < 4; ++mt)
                kf[mt] = *(const bf16x8*)&K_lds[(mt * 16 + l16) * 256 + (((4 * c + quad) ^ sw) * 8)];
            #pragma unroll
            for (int mt = 0; mt < 4; ++mt)
                st[mt] = __builtin_amdgcn_mfma_f32_16x16x32_bf16(kf[mt], qf[c], st[mt], 0, 0, 0);
        }
        __builtin_amdgcn_s_setprio(0);

        // softcap + exp(static m=30); P -> LDS
        #pragma unroll
        for (int mt = 0; mt < 4; ++mt)
            #pragma unroll
            for (int r = 0; r < 4; ++r) {
                int sp = sb + mt * 16 + quad * 4 + r;
                float e2 = __expf(st[mt][r] * 0.0025f);         // exp(2*logits/800)
                float p = __expf(20.0f - 100.0f / (e2 + 1.0f)); // exp(softcap - 30)
                bool valid = (sp <= tq) && (tq - sp < WIN);
                p = valid ? p : 0.0f;
                l_run += p;
                P_lds[l16 * PSTR + mt * 16 + quad * 4 + r] = f2bf(p);
            }

        // O += P · V^T
        #pragma unroll
        for (int c = 0; c < 2; ++c) {
            bf16x8 pf = *(const bf16x8*)&P_lds[l16 * PSTR + 32 * c + quad * 8];
            __builtin_amdgcn_s_setprio(1);
            #pragma unroll
            for (int nt = 0; nt < 16; ++nt) {
                bf16x8 vf = *(const bf16x8*)&VT_lds[(nt * 16 + l16) * 64 + (((4 * c + quad) ^ sw) * 8)];
                o[nt] = __builtin_amdgcn_mfma_f32_16x16x32_bf16(pf, vf, o[nt], 0, 0, 0);
            }
            __builtin_amdgcn_s_setprio(0);
        }
    }

    l_run += __shfl_xor(l_run, 16);
    l_run += __shfl_xor(l_run, 32);
    float linv[4];
    #pragma unroll
    for (int r = 0; r < 4; ++r) linv[r] = 1.0f / __shfl(l_run, quad * 4 + r);

    // coalesced epilogue: O -> LDS (row-major 16x256, stride 264) -> dwordx4
    __syncthreads();
    unsigned short* W = SMEM + wave * (16 * 264);
    #pragma unroll
    for (int nt = 0; nt < 16; ++nt)
        #pragma unroll
        for (int r = 0; r < 4; ++r)
            W[(quad * 4 + r) * 264 + nt * 16 + l16] = f2bf(o[nt][r] * linv[r]);
    const int lr = lane >> 2, lc = (lane & 3) * 64;
    unsigned short* ob = out + (size_t)(b * T_SEQ + t0 + woff + lr) * 2048 + h * 256 + lc;
    #pragma unroll
    for (int j = 0; j < 8; ++j)
        *(uint4*)(ob + j * 8) = *(const uint4*)&W[lr * 264 + lc + j * 8];
}

// ------------------------------------------------------------- launch
extern "C" void kernel_launch(void* const* d_in, const int* in_sizes, int n_in,
                              void* d_out, int out_size, void* d_ws, size_t ws_size,
                              hipStream_t stream) {
    const void* x   = d_in[0];
    const int*  sp  = (const int*)d_in[1];
    const void* wq  = d_in[3];
    const void* wk  = d_in[4];
    const void* wv  = d_in[5];
    const void* wo  = d_in[6];
    const void* qsc = d_in[7];
    const void* ksc = d_in[8];

    unsigned short* ws = (unsigned short*)d_ws;
    int*            flag = (int*)ws;
    unsigned short* qkv  = (unsigned short*)d_out;
    dim3 blk(256);

    const size_t NEED = (size_t)(2048 + 8388608 + 8388608) * sizeof(unsigned short);

    detect_dtype<<<1, 64, 0, stream>>>((const unsigned short*)x, flag);

    if (ws_size >= NEED) {
        unsigned short* xhat = ws + 2048;                      // 4096x2048
        unsigned short* wT   = xhat + (size_t)4096 * 2048;     // 4096x2048 stacked
        unsigned short* abuf = xhat;                           // reuse after QKV
        unsigned short* vtb  = wT;                             // reuse after QKV GEMM
        unsigned short* woT  = wT + (size_t)2048 * 2048;       // after vt (4M us)

        convert_to_bf16<<<4096, blk, 0, stream>>>(x, xhat, flag, 4096 * 2048);

        // stacked B^T: one fused transpose for wq/wk/wv
        transpose_qkv_w<<<dim3(128, 64), blk, 0, stream>>>(wq, wk, wv, wT, flag);

        // fused QKV GEMM on 256^2 tile: 16x16 = 256 blocks, 512 threads
        gemm256_bf16<<<256, 512, 0, stream>>>(xhat, wT, qkv,
                                              4096, 4096, 2048, 0, 16, flag, 1);

        finalize_qk<<<12288, blk, 0, stream>>>(qkv, sp, qsc, ksc, flag);

        build_vt<<<dim3(64, 8, 8), blk, 0, stream>>>(qkv, vtb);
        attn_mfma<<<512, blk, 0, stream>>>(qkv, vtb, abuf);

        transpose_cvt<<<dim3(64, 64), blk, 0, stream>>>(wo, woT, flag, 2048, 2048);
        gemm_bf16<<<dim3(16, 32), blk, 0, stream>>>(abuf, woT, d_out,
                                                    4096, 2048, 2048, 0, flag, 0);
    } else {
        // fallback: two-GEMM layout, ~24.6 MB ws
        unsigned short* reg1 = ws + 2048;                      // 8,388,608 us
        unsigned short* reg2 = reg1 + (size_t)4096 * 2048;     // 4,194,304 us
        unsigned short* xhat = reg1;
        unsigned short* abuf = reg1;

        convert_to_bf16<<<4096, blk, 0, stream>>>(x, xhat, flag, 4096 * 2048);

        transpose_cvt<<<dim3(64, 64), blk, 0, stream>>>(wq, reg2, flag, 2048, 2048);
        gemm_bf16<<<dim3(16, 32), blk, 0, stream>>>(xhat, reg2, qkv,
                                                    4096, 4096, 2048, 0, flag, 1);
        transpose_cvt<<<dim3(32, 64), blk, 0, stream>>>(wk, reg2,                     flag, 2048, 1024);
        transpose_cvt<<<dim3(32, 64), blk, 0, stream>>>(wv, reg2 + (size_t)1024*2048, flag, 2048, 1024);
        gemm_bf16<<<dim3(16, 32), blk, 0, stream>>>(xhat, reg2, qkv,
                                                    4096, 4096, 2048, 2048, flag, 1);

        finalize_qk<<<12288, blk, 0, stream>>>(qkv, sp, qsc, ksc, flag);

        build_vt<<<dim3(64, 8, 8), blk, 0, stream>>>(qkv, reg2);
        attn_mfma<<<512, blk, 0, stream>>>(qkv, reg2, abuf);

        transpose_cvt<<<dim3(64, 64), blk, 0, stream>>>(wo, reg2, flag, 2048, 2048);
        gemm_bf16<<<dim3(16, 32), blk, 0, stream>>>(abuf, reg2, d_out,
                                                    4096, 2048, 2048, 0, flag, 0);
    }
}

// Round 5
// 359.062 us; speedup vs baseline: 1.3449x; 1.0084x over previous
//
#include <hip/hip_runtime.h>

#define T_SEQ 2048
#define NHEADS 8
#define NKV 4
#define HD 256
#define WIN 512

typedef __bf16 bf16x8 __attribute__((ext_vector_type(8)));
typedef float f32x4 __attribute__((ext_vector_type(4)));

__device__ __forceinline__ float bf2f(unsigned short u) {
    return __uint_as_float(((unsigned int)u) << 16);
}
__device__ __forceinline__ unsigned short f2bf(float f) {
    unsigned int u = __float_as_uint(f);
    u += 0x7fffu + ((u >> 16) & 1u);
    return (unsigned short)(u >> 16);
}

#define GLOAD_LDS16(gptr, lptr)                                            \
    __builtin_amdgcn_global_load_lds(                                      \
        (const __attribute__((address_space(1))) unsigned int*)(gptr),     \
        (__attribute__((address_space(3))) unsigned int*)(lptr), 16, 0, 0)

// ------------------------------------------------------------- dtype detect
__global__ void detect_dtype(const unsigned short* __restrict__ x, int* flag) {
    int tid = threadIdx.x;
    int cnt = 0;
    for (int i = 0; i < 64; ++i) {
        unsigned short u = x[2 * (tid * 64 + i)];
        int e = (u >> 7) & 0xFF;
        cnt += (e >= 100 && e <= 140) ? 1 : 0;
    }
    #pragma unroll
    for (int o = 32; o >= 1; o >>= 1) cnt += __shfl_xor(cnt, o);
    if (tid == 0) *flag = (cnt > 2048) ? 1 : 0;
}

// ------------------------------------------------------------- convert
__global__ __launch_bounds__(256) void convert_to_bf16(
    const void* __restrict__ src, unsigned short* __restrict__ dst,
    const int* __restrict__ flag, int n)
{
    int i = (blockIdx.x * 256 + threadIdx.x) * 8;
    if (i >= n) return;
    if (*flag) {
        *(uint4*)&dst[i] = *(const uint4*)((const unsigned short*)src + i);
    } else {
        const float* s = (const float*)src + i;
        unsigned short v[8];
        #pragma unroll
        for (int j = 0; j < 8; ++j) v[j] = f2bf(s[j]);
        *(uint4*)&dst[i] = *(uint4*)v;
    }
}

// ------------------------------------------------------------- transpose+cvt
__global__ __launch_bounds__(256) void transpose_cvt(
    const void* __restrict__ src, unsigned short* __restrict__ dst,
    const int* __restrict__ flag, int R, int C)
{
    __shared__ unsigned short tile[32][33];
    const int t = threadIdx.x;
    const int c = t & 31, r8 = t >> 5;
    const int bx = blockIdx.x, by = blockIdx.y;
    const int isb = *flag;
    #pragma unroll
    for (int i = 0; i < 4; ++i) {
        int r = r8 + i * 8;
        size_t idx = (size_t)(by * 32 + r) * C + bx * 32 + c;
        tile[r][c] = isb ? ((const unsigned short*)src)[idx]
                         : f2bf(((const float*)src)[idx]);
    }
    __syncthreads();
    #pragma unroll
    for (int i = 0; i < 4; ++i) {
        int r = r8 + i * 8;
        dst[(size_t)(bx * 32 + r) * R + by * 32 + c] = tile[c][r];
    }
}

// --------------------------------------------- fused wq/wk/wv transpose+cvt
__global__ __launch_bounds__(256) void transpose_qkv_w(
    const void* __restrict__ wq, const void* __restrict__ wk,
    const void* __restrict__ wv, unsigned short* __restrict__ dst,
    const int* __restrict__ flag)
{
    __shared__ unsigned short tile[32][33];
    const int t = threadIdx.x;
    const int c = t & 31, r8 = t >> 5;
    const int bx = blockIdx.x, by = blockIdx.y;
    const void* src; int C, rowoff, cb;
    if (bx < 64)      { src = wq; C = 2048; rowoff = 0;    cb = bx; }
    else if (bx < 96) { src = wk; C = 1024; rowoff = 2048; cb = bx - 64; }
    else              { src = wv; C = 1024; rowoff = 3072; cb = bx - 96; }
    const int isb = *flag;
    #pragma unroll
    for (int i = 0; i < 4; ++i) {
        int r = r8 + i * 8;
        size_t idx = (size_t)(by * 32 + r) * C + cb * 32 + c;
        tile[r][c] = isb ? ((const unsigned short*)src)[idx]
                         : f2bf(((const float*)src)[idx]);
    }
    __syncthreads();
    #pragma unroll
    for (int i = 0; i < 4; ++i) {
        int r = r8 + i * 8;
        dst[(size_t)(rowoff + cb * 32 + r) * 2048 + by * 32 + c] = tile[c][r];
    }
}

// ------------------------------------------------------------- GEMM 128 (m97)
// kept for the small-workspace fallback path
__global__ __launch_bounds__(256) void gemm_bf16(
    const unsigned short* __restrict__ A,
    const unsigned short* __restrict__ Bt,
    void* __restrict__ C,
    int M, int Ntot, int K, int n_base,
    const int* __restrict__ flag, int force_bf16)
{
    __shared__ __align__(16) unsigned short As[128 * 32];
    __shared__ __align__(16) unsigned short Bs[128 * 32];
    const int tid = threadIdx.x;
    const int n0 = blockIdx.x * 128;
    const int m0 = blockIdx.y * 128;
    const int wave = tid >> 6;
    const int lane = tid & 63;
    const int wm = (wave >> 1) * 64;
    const int wn = (wave & 1) * 64;
    const int quad = lane >> 4;
    const int l16 = lane & 15;
    const int obf = force_bf16 | *flag;

    f32x4 acc[4][4];
    #pragma unroll
    for (int i = 0; i < 4; ++i)
        #pragma unroll
        for (int j = 0; j < 4; ++j)
            acc[i][j] = f32x4{0.f, 0.f, 0.f, 0.f};

    for (int kk = 0; kk < K; kk += 32) {
        #pragma unroll
        for (int i = 0; i < 2; ++i) {
            int ch = tid + i * 256;
            int row = ch >> 2;
            int ko = (ch & 3) * 8;
            GLOAD_LDS16(&A[(size_t)(m0 + row) * K + kk + ko],  &As[ch * 8]);
            GLOAD_LDS16(&Bt[(size_t)(n0 + row) * K + kk + ko], &Bs[ch * 8]);
        }
        __syncthreads();
        bf16x8 af[4], bfr[4];
        #pragma unroll
        for (int mi = 0; mi < 4; ++mi)
            af[mi] = *(const bf16x8*)&As[(wm + mi * 16 + l16) * 32 + quad * 8];
        #pragma unroll
        for (int ni = 0; ni < 4; ++ni)
            bfr[ni] = *(const bf16x8*)&Bs[(wn + ni * 16 + l16) * 32 + quad * 8];
        #pragma unroll
        for (int mi = 0; mi < 4; ++mi)
            #pragma unroll
            for (int ni = 0; ni < 4; ++ni)
                acc[mi][ni] = __builtin_amdgcn_mfma_f32_16x16x32_bf16(
                    af[mi], bfr[ni], acc[mi][ni], 0, 0, 0);
        __syncthreads();
    }

    #pragma unroll
    for (int mi = 0; mi < 4; ++mi)
        #pragma unroll
        for (int ni = 0; ni < 4; ++ni)
            #pragma unroll
            for (int r = 0; r < 4; ++r) {
                int row = m0 + wm + mi * 16 + quad * 4 + r;
                int col = n_base + n0 + wn + ni * 16 + l16;
                size_t idx = (size_t)row * Ntot + col;
                if (obf) ((unsigned short*)C)[idx] = f2bf(acc[mi][ni][r]);
                else     ((float*)C)[idx]          = acc[mi][ni][r];
            }
}

// ------------------------------------------------------------- GEMM 256, 8-phase
// m201-style schedule: per K-tile 4 quadrant-phases of 16 MFMA; one half-tile
// staged per phase into the slot freed one phase earlier (inter-phase barrier
// makes it race-free); vmcnt(6) only at phases 3/7. Halves: A keyed on global
// row bit-6, B on bit-5 with a permuted LDS row map (DMA dest stays linear).
// Swizzle involution (rule 21) identical to the verified R4 kernel.
__global__ __launch_bounds__(512, 2) void gemm256_bf16(
    const unsigned short* __restrict__ A,
    const unsigned short* __restrict__ Bt,
    void* __restrict__ C,
    int M, int Ntot, int K, int n_base, int gx,
    const int* __restrict__ flag, int force_bf16)
{
    __shared__ __align__(16) unsigned short A_lds[2][256 * 64];
    __shared__ __align__(16) unsigned short B_lds[2][256 * 64];

    const int tid = threadIdx.x;
    const int cpx = gridDim.x >> 3;
    const int swzb = (blockIdx.x & 7) * cpx + (blockIdx.x >> 3);
    const int bx = swzb % gx, by = swzb / gx;
    const int n0 = bx * 256, m0 = by * 256;

    const int wave = tid >> 6, lane = tid & 63;
    const int wr = wave >> 2, wc = wave & 3;          // 2M x 4N
    const int quad = lane >> 4, l16 = lane & 15;
    const int sw7 = l16 & 7;
    const int obf = force_bf16 | *flag;

    const int trow = tid >> 3;            // 0..63
    const int tg   = tid & 7;             // granule 0..7
    const int tsw  = (tg ^ (trow & 7)) * 8;

    f32x4 acc[8][4];
    #pragma unroll
    for (int i = 0; i < 8; ++i)
        #pragma unroll
        for (int j = 0; j < 4; ++j)
            acc[i][j] = f32x4{0.f, 0.f, 0.f, 0.f};

    const int NT = K >> 6;        // K-tiles of 64 (assumed even, >= 4)
    const int NI = NT >> 1;

    // A half hm: global rows {hm*64..hm*64+63} U {128+hm*64..128+hm*64+63}
    //   -> LDS rows hm*128 .. hm*128+127 (linear dest)
#define STAGE_A(d_, hm_, kt_)                                                  \
    do { _Pragma("unroll") for (int j = 0; j < 2; ++j) {                       \
        int r_ = j * 128 + (hm_) * 64 + trow;                                  \
        GLOAD_LDS16(&A[(size_t)(m0 + r_) * K + (kt_) * 64 + tsw],              \
                    &A_lds[d_][((hm_) * 128 + j * 64 + trow) * 64 + tg * 8]);  \
    } } while (0)

    // B half hn: global rows r with ((r>>5)&1)==hn -> LDS rows hn*128+perm
#define STAGE_B(d_, hn_, kt_)                                                  \
    do { _Pragma("unroll") for (int j = 0; j < 2; ++j) {                       \
        int w2_ = j * 64 + trow;                                               \
        int r_ = (w2_ >> 5) * 64 + (hn_) * 32 + (w2_ & 31);                    \
        GLOAD_LDS16(&Bt[(size_t)(n0 + r_) * K + (kt_) * 64 + tsw],             \
                    &B_lds[d_][((hn_) * 128 + w2_) * 64 + tg * 8]);            \
    } } while (0)

    bf16x8 a[4][2], b0[2][2], b1[2][2];

#define LDA_H(d_, hm_)                                                         \
    do { _Pragma("unroll") for (int mi = 0; mi < 4; ++mi)                      \
         _Pragma("unroll") for (int ks = 0; ks < 2; ++ks)                      \
            a[mi][ks] = *(const bf16x8*)&A_lds[d_][                            \
                ((hm_) * 128 + wr * 64 + mi * 16 + l16) * 64                   \
                + (((ks * 4 + quad) ^ sw7) * 8)]; } while (0)

#define LDB_H(d_, hn_, bb_)                                                    \
    do { _Pragma("unroll") for (int ni = 0; ni < 2; ++ni)                      \
         _Pragma("unroll") for (int ks = 0; ks < 2; ++ks)                      \
            bb_[ni][ks] = *(const bf16x8*)&B_lds[d_][                          \
                ((hn_) * 128 + wc * 32 + ni * 16 + l16) * 64                   \
                + (((ks * 4 + quad) ^ sw7) * 8)]; } while (0)

#define MFMAQ(hm_, hn_, bb_)                                                   \
    do { __builtin_amdgcn_s_setprio(1);                                        \
         _Pragma("unroll") for (int mi = 0; mi < 4; ++mi)                      \
         _Pragma("unroll") for (int ni = 0; ni < 2; ++ni)                      \
         _Pragma("unroll") for (int ks = 0; ks < 2; ++ks)                      \
            acc[(hm_) * 4 + mi][(hn_) * 2 + ni] =                              \
                __builtin_amdgcn_mfma_f32_16x16x32_bf16(                       \
                    a[mi][ks], bb_[ni][ks],                                    \
                    acc[(hm_) * 4 + mi][(hn_) * 2 + ni], 0, 0, 0);             \
         __builtin_amdgcn_s_setprio(0); } while (0)

#define BAR() do { __builtin_amdgcn_sched_barrier(0);                          \
                   __builtin_amdgcn_s_barrier();                               \
                   __builtin_amdgcn_sched_barrier(0); } while (0)
#define LGKM0() do { asm volatile("s_waitcnt lgkmcnt(0)" ::: "memory");        \
                     __builtin_amdgcn_sched_barrier(0); } while (0)
#define VMC(n_) asm volatile("s_waitcnt vmcnt(" #n_ ")" ::: "memory")

    // prologue: tile0 (4 halves) + tile1 (3 halves; A1 comes at ph0)
    STAGE_A(0, 0, 0); STAGE_B(0, 0, 0); STAGE_B(0, 1, 0); STAGE_A(0, 1, 0);
    STAGE_A(1, 0, 1); STAGE_B(1, 0, 1); STAGE_B(1, 1, 1);
    VMC(6);                    // drains 8 oldest = all of tile0
    BAR();

    for (int i = 0; i < NI; ++i) {
        const int t2 = 2 * i + 2, t3 = 2 * i + 3;
        const bool s2 = t2 < NT, s3 = t3 < NT;

        // ph0: Q(d0,hm0,hn0) — reads A0,B0; stage A1(d1) <- tile 2i+1
        LDA_H(0, 0); LDB_H(0, 0, b0);
        STAGE_A(1, 1, 2 * i + 1);
        BAR(); LGKM0(); MFMAQ(0, 0, b0);
        BAR();
        // ph1: Q(d0,hm0,hn1) — reads B1; stage A0(d0) <- t2
        LDB_H(0, 1, b1);
        if (s2) STAGE_A(0, 0, t2);
        BAR(); LGKM0(); MFMAQ(0, 1, b1);
        BAR();
        // ph2: Q(d0,hm1,hn1) — reads A1; stage B0(d0) <- t2
        LDA_H(0, 1);
        if (s2) STAGE_B(0, 0, t2);
        BAR(); LGKM0(); MFMAQ(1, 1, b1);
        BAR();
        // ph3: Q(d0,hm1,hn0) — all held; stage B1(d0) <- t2; gate
        if (s2) STAGE_B(0, 1, t2);
        BAR(); LGKM0(); MFMAQ(1, 0, b0);
        if (s2) { VMC(6); } else { VMC(0); }   // tile 2i+1 fully resident
        BAR();
        // ph4: Q(d1,hm0,hn0); stage A1(d0) <- t2
        LDA_H(1, 0); LDB_H(1, 0, b0);
        if (s2) STAGE_A(0, 1, t2);
        BAR(); LGKM0(); MFMAQ(0, 0, b0);
        BAR();
        // ph5: Q(d1,hm0,hn1); stage A0(d1) <- t3
        LDB_H(1, 1, b1);
        if (s3) STAGE_A(1, 0, t3);
        BAR(); LGKM0(); MFMAQ(0, 1, b1);
        BAR();
        // ph6: Q(d1,hm1,hn1); stage B0(d1) <- t3
        LDA_H(1, 1);
        if (s3) STAGE_B(1, 0, t3);
        BAR(); LGKM0(); MFMAQ(1, 1, b1);
        BAR();
        // ph7: Q(d1,hm1,hn0); stage B1(d1) <- t3; gate
        if (s3) STAGE_B(1, 1, t3);
        BAR(); LGKM0(); MFMAQ(1, 0, b0);
        if (s3) { VMC(6); } else { VMC(0); }   // tile 2i+2 fully resident
        BAR();
    }

#undef STAGE_A
#undef STAGE_B
#undef LDA_H
#undef LDB_H
#undef MFMAQ
#undef BAR
#undef LGKM0
#undef VMC

    #pragma unroll
    for (int mi = 0; mi < 8; ++mi)
        #pragma unroll
        for (int ni = 0; ni < 4; ++ni)
            #pragma unroll
            for (int r = 0; r < 4; ++r) {
                int row = m0 + wr * 128 + mi * 16 + quad * 4 + r;
                int col = n_base + n0 + wc * 64 + ni * 16 + l16;
                size_t idx = (size_t)row * Ntot + col;
                if (obf) ((unsigned short*)C)[idx] = f2bf(acc[mi][ni][r]);
                else     ((float*)C)[idx]          = acc[mi][ni][r];
            }
}

// ------------------------------------------------------------- finalize
__global__ __launch_bounds__(256) void finalize_qk(
    unsigned short* __restrict__ qkv,
    const int* __restrict__ segment_pos,
    const void* __restrict__ qs_raw,
    const void* __restrict__ ks_raw,
    const int* __restrict__ flag)
{
    const int w = blockIdx.x * 4 + (threadIdx.x >> 6);
    const int lane = threadIdx.x & 63;
    const int b = w / (T_SEQ * 12);
    const int rem = w % (T_SEQ * 12);
    const int t = rem / 12;
    const int slot = rem % 12;
    const bool isq = slot < 8;
    const int col0 = isq ? slot * 256 : 2048 + (slot - 8) * 256;
    unsigned short* p = qkv + (size_t)(b * T_SEQ + t) * 4096 + col0;
    const int isb = *flag;

    float e[4];
    #pragma unroll
    for (int j = 0; j < 4; ++j) e[j] = bf2f(p[lane + 64 * j]);
    float ss = e[0] * e[0] + e[1] * e[1] + e[2] * e[2] + e[3] * e[3];
    #pragma unroll
    for (int o = 32; o >= 1; o >>= 1) ss += __shfl_xor(ss, o);
    const float rn = rsqrtf(ss * (1.0f / 256.0f) + 1e-6f);
    const void* scp = isq ? qs_raw : ks_raw;
    float nrm[4];
    #pragma unroll
    for (int j = 0; j < 4; ++j) {
        float sc = isb ? bf2f(((const unsigned short*)scp)[lane + 64 * j])
                       : ((const float*)scp)[lane + 64 * j];
        nrm[j] = e[j] * rn * (1.0f + sc);
    }

    const int pos = segment_pos[b * T_SEQ + t];
    #pragma unroll
    for (int pp = 0; pp < 2; ++pp) {
        const int i = lane + 64 * pp;
        const float inv_ts = __expf((float)i * -0.07195578415606293f);
        float s, c;
        __sincosf((float)pos * inv_ts, &s, &c);
        const float x1 = nrm[pp], x2 = nrm[pp + 2];
        p[i]       = f2bf(x1 * c - x2 * s);
        p[i + 128] = f2bf(x2 * c + x1 * s);
    }
}

// ------------------------------------------------------------- V transpose
__global__ __launch_bounds__(256) void build_vt(
    const unsigned short* __restrict__ qkv, unsigned short* __restrict__ vt)
{
    __shared__ unsigned short tile[32][33];
    const int bkv = blockIdx.z;
    const int b = bkv >> 2, kv = bkv & 3;
    const int s0 = blockIdx.x * 32, d0 = blockIdx.y * 32;
    const int c = threadIdx.x & 31, r8 = threadIdx.x >> 5;
    #pragma unroll
    for (int i = 0; i < 4; ++i) {
        int r = r8 + i * 8;
        tile[r][c] = qkv[(size_t)(b * T_SEQ + s0 + r) * 4096 + 3072 + kv * 256 + d0 + c];
    }
    __syncthreads();
    #pragma unroll
    for (int i = 0; i < 4; ++i) {
        int r = r8 + i * 8;
        vt[((size_t)bkv * 256 + d0 + r) * T_SEQ + s0 + c] = tile[c][r];
    }
}

// ------------------------------------------------------------- MFMA attention
#define PSTR 80
__global__ __launch_bounds__(256, 2) void attn_mfma(
    const unsigned short* __restrict__ qkv,
    const unsigned short* __restrict__ vt,
    unsigned short* __restrict__ out)
{
    __shared__ __align__(16) unsigned short SMEM[16384 + 16384 + 4 * 16 * PSTR];
    unsigned short* K_lds  = SMEM;            // 64 x 256 (swizzled)
    unsigned short* VT_lds = SMEM + 16384;    // 256 x 64 (swizzled)

    const int tid = threadIdx.x;
    const int wave = tid >> 6, lane = tid & 63;
    const int l16 = lane & 15, quad = lane >> 4;
    const int sw = l16 & 7;
    const int bkv = blockIdx.x & 7;           // XCD swizzle: same bkv -> same XCD
    const int qt  = blockIdx.x >> 3;
    const int b = bkv >> 2, kvh = bkv & 3;
    const int t0 = qt * 32;
    const int h = kvh * 2 + (wave >> 1);
    const int woff = (wave & 1) * 16;
    const int tq = t0 + woff + l16;
    unsigned short* P_lds = SMEM + 32768 + wave * 16 * PSTR;

    bf16x8 qf[8];
    {
        const unsigned short* qp =
            qkv + (size_t)(b * T_SEQ + tq) * 4096 + h * 256 + quad * 8;
        #pragma unroll
        for (int c = 0; c < 8; ++c) qf[c] = *(const bf16x8*)(qp + 32 * c);
    }

    f32x4 o[16];
    #pragma unroll
    for (int nt = 0; nt < 16; ++nt) o[nt] = f32x4{0.f, 0.f, 0.f, 0.f};
    float l_run = 0.f;

    int s_lo = t0 - (WIN - 1); if (s_lo < 0) s_lo = 0;
    const int s_base = s_lo & ~63;
    const int s_last = t0 + 31;
    const int tqmin = t0 + woff;
    const int tqmax = tqmin + 15;
    const int wlo   = tqmin - (WIN - 1);      // lowest key this wave can see
    const size_t kgbase = (size_t)b * T_SEQ * 4096 + 2048 + kvh * 256;
    const size_t vgbase = (size_t)bkv * 256 * T_SEQ;

    for (int sb = s_base; sb <= s_last; sb += 64) {
        __syncthreads();   // previous tile fully consumed

        // K tile: linear LDS dest, source column pre-swizzled (m173 pattern)
        #pragma unroll
        for (int i = 0; i < 8; ++i) {
            int ch = tid + 256 * i;
            int row = ch >> 5, e8 = ch & 31;
            GLOAD_LDS16(&qkv[kgbase + (size_t)(sb + row) * 4096
                             + ((e8 ^ (row & 7)) * 8)],
                        &K_lds[ch * 8]);
        }
        // VT tile
        #pragma unroll
        for (int i = 0; i < 8; ++i) {
            int ch = tid + 256 * i;
            int dr = ch >> 3, e8 = ch & 7;
            GLOAD_LDS16(&vt[vgbase + (size_t)dr * T_SEQ + sb
                            + ((e8 ^ (dr & 7)) * 8)],
                        &VT_lds[ch * 8]);
        }
        __syncthreads();   // drains vmcnt(0): tile resident in LDS

        if (sb > tqmax || sb + 63 < wlo) continue;   // wave-uniform skip

        // S^T = K · Q^T
        f32x4 st[4];
        #pragma unroll
        for (int mt = 0; mt < 4; ++mt) st[mt] = f32x4{0.f, 0.f, 0.f, 0.f};
        __builtin_amdgcn_s_setprio(1);
        #pragma unroll
        for (int c = 0; c < 8; ++c) {
            bf16x8 kf[4];
            #pragma unroll
            for (int mt = 0; mt < 4; ++mt)
                kf[mt] = *(const bf16x8*)&K_lds[(mt * 16 + l16) * 256 + (((4 * c + quad) ^ sw) * 8)];
            #pragma unroll
            for (int mt = 0; mt < 4; ++mt)
                st[mt] = __builtin_amdgcn_mfma_f32_16x16x32_bf16(kf[mt], qf[c], st[mt], 0, 0, 0);
        }
        __builtin_amdgcn_s_setprio(0);

        // softcap + exp(static m=30); P -> LDS
        #pragma unroll
        for (int mt = 0; mt < 4; ++mt)
            #pragma unroll
            for (int r = 0; r < 4; ++r) {
                int sp = sb + mt * 16 + quad * 4 + r;
                float e2 = __expf(st[mt][r] * 0.0025f);         // exp(2*logits/800)
                float p = __expf(20.0f - 100.0f / (e2 + 1.0f)); // exp(softcap - 30)
                bool valid = (sp <= tq) && (tq - sp < WIN);
                p = valid ? p : 0.0f;
                l_run += p;
                P_lds[l16 * PSTR + mt * 16 + quad * 4 + r] = f2bf(p);
            }

        // O += P · V^T
        #pragma unroll
        for (int c = 0; c < 2; ++c) {
            bf16x8 pf = *(const bf16x8*)&P_lds[l16 * PSTR + 32 * c + quad * 8];
            __builtin_amdgcn_s_setprio(1);
            #pragma unroll
            for (int nt = 0; nt < 16; ++nt) {
                bf16x8 vf = *(const bf16x8*)&VT_lds[(nt * 16 + l16) * 64 + (((4 * c + quad) ^ sw) * 8)];
                o[nt] = __builtin_amdgcn_mfma_f32_16x16x32_bf16(pf, vf, o[nt], 0, 0, 0);
            }
            __builtin_amdgcn_s_setprio(0);
        }
    }

    l_run += __shfl_xor(l_run, 16);
    l_run += __shfl_xor(l_run, 32);
    float linv[4];
    #pragma unroll
    for (int r = 0; r < 4; ++r) linv[r] = 1.0f / __shfl(l_run, quad * 4 + r);

    // coalesced epilogue: O -> LDS (row-major 16x256, stride 264) -> dwordx4
    __syncthreads();
    unsigned short* W = SMEM + wave * (16 * 264);
    #pragma unroll
    for (int nt = 0; nt < 16; ++nt)
        #pragma unroll
        for (int r = 0; r < 4; ++r)
            W[(quad * 4 + r) * 264 + nt * 16 + l16] = f2bf(o[nt][r] * linv[r]);
    const int lr = lane >> 2, lc = (lane & 3) * 64;
    unsigned short* ob = out + (size_t)(b * T_SEQ + t0 + woff + lr) * 2048 + h * 256 + lc;
    #pragma unroll
    for (int j = 0; j < 8; ++j)
        *(uint4*)(ob + j * 8) = *(const uint4*)&W[lr * 264 + lc + j * 8];
}

// ------------------------------------------------------------- launch
extern "C" void kernel_launch(void* const* d_in, const int* in_sizes, int n_in,
                              void* d_out, int out_size, void* d_ws, size_t ws_size,
                              hipStream_t stream) {
    const void* x   = d_in[0];
    const int*  sp  = (const int*)d_in[1];
    const void* wq  = d_in[3];
    const void* wk  = d_in[4];
    const void* wv  = d_in[5];
    const void* wo  = d_in[6];
    const void* qsc = d_in[7];
    const void* ksc = d_in[8];

    unsigned short* ws = (unsigned short*)d_ws;
    int*            flag = (int*)ws;
    unsigned short* qkv  = (unsigned short*)d_out;
    dim3 blk(256);

    const size_t NEED = (size_t)(2048 + 8388608 + 8388608) * sizeof(unsigned short);

    detect_dtype<<<1, 64, 0, stream>>>((const unsigned short*)x, flag);

    if (ws_size >= NEED) {
        unsigned short* xhat = ws + 2048;                      // 4096x2048
        unsigned short* wT   = xhat + (size_t)4096 * 2048;     // 4096x2048 stacked
        unsigned short* abuf = xhat;                           // reuse after QKV
        unsigned short* vtb  = wT;                             // reuse after QKV GEMM
        unsigned short* woT  = wT + (size_t)2048 * 2048;       // after vt (4M us)

        convert_to_bf16<<<4096, blk, 0, stream>>>(x, xhat, flag, 4096 * 2048);

        // stacked B^T: one fused transpose for wq/wk/wv
        transpose_qkv_w<<<dim3(128, 64), blk, 0, stream>>>(wq, wk, wv, wT, flag);

        // fused QKV GEMM, 256^2 8-phase: 16x16 = 256 blocks, 512 threads
        gemm256_bf16<<<256, 512, 0, stream>>>(xhat, wT, qkv,
                                              4096, 4096, 2048, 0, 16, flag, 1);

        finalize_qk<<<12288, blk, 0, stream>>>(qkv, sp, qsc, ksc, flag);

        build_vt<<<dim3(64, 8, 8), blk, 0, stream>>>(qkv, vtb);
        attn_mfma<<<512, blk, 0, stream>>>(qkv, vtb, abuf);

        transpose_cvt<<<dim3(64, 64), blk, 0, stream>>>(wo, woT, flag, 2048, 2048);
        // wo GEMM on the same 8-phase kernel: 8x16 = 128 blocks (128%8==0)
        gemm256_bf16<<<128, 512, 0, stream>>>(abuf, woT, d_out,
                                              4096, 2048, 2048, 0, 8, flag, 0);
    } else {
        // fallback: two-GEMM layout, ~24.6 MB ws
        unsigned short* reg1 = ws + 2048;                      // 8,388,608 us
        unsigned short* reg2 = reg1 + (size_t)4096 * 2048;     // 4,194,304 us
        unsigned short* xhat = reg1;
        unsigned short* abuf = reg1;

        convert_to_bf16<<<4096, blk, 0, stream>>>(x, xhat, flag, 4096 * 2048);

        transpose_cvt<<<dim3(64, 64), blk, 0, stream>>>(wq, reg2, flag, 2048, 2048);
        gemm_bf16<<<dim3(16, 32), blk, 0, stream>>>(xhat, reg2, qkv,
                                                    4096, 4096, 2048, 0, flag, 1);
        transpose_cvt<<<dim3(32, 64), blk, 0, stream>>>(wk, reg2,                     flag, 2048, 1024);
        transpose_cvt<<<dim3(32, 64), blk, 0, stream>>>(wv, reg2 + (size_t)1024*2048, flag, 2048, 1024);
        gemm_bf16<<<dim3(16, 32), blk, 0, stream>>>(xhat, reg2, qkv,
                                                    4096, 4096, 2048, 2048, flag, 1);

        finalize_qk<<<12288, blk, 0, stream>>>(qkv, sp, qsc, ksc, flag);

        build_vt<<<dim3(64, 8, 8), blk, 0, stream>>>(qkv, reg2);
        attn_mfma<<<512, blk, 0, stream>>>(qkv, reg2, abuf);

        transpose_cvt<<<dim3(64, 64), blk, 0, stream>>>(wo, reg2, flag, 2048, 2048);
        gemm_bf16<<<dim3(16, 32), blk, 0, stream>>>(abuf, reg2, d_out,
                                                    4096, 2048, 2048, 0, flag, 0);
    }
}

// Round 6
// 350.894 us; speedup vs baseline: 1.3762x; 1.0233x over previous
//
#include <hip/hip_runtime.h>

#define T_SEQ 2048
#define NHEADS 8
#define NKV 4
#define HD 256
#define WIN 512

typedef __bf16 bf16x8 __attribute__((ext_vector_type(8)));
typedef float f32x4 __attribute__((ext_vector_type(4)));

__device__ __forceinline__ float bf2f(unsigned short u) {
    return __uint_as_float(((unsigned int)u) << 16);
}
__device__ __forceinline__ unsigned short f2bf(float f) {
    unsigned int u = __float_as_uint(f);
    u += 0x7fffu + ((u >> 16) & 1u);
    return (unsigned short)(u >> 16);
}

#define GLOAD_LDS16(gptr, lptr)                                            \
    __builtin_amdgcn_global_load_lds(                                      \
        (const __attribute__((address_space(1))) unsigned int*)(gptr),     \
        (__attribute__((address_space(3))) unsigned int*)(lptr), 16, 0, 0)

// ------------------------------------------------------------- dtype detect
__global__ void detect_dtype(const unsigned short* __restrict__ x, int* flag) {
    int tid = threadIdx.x;
    int cnt = 0;
    for (int i = 0; i < 64; ++i) {
        unsigned short u = x[2 * (tid * 64 + i)];
        int e = (u >> 7) & 0xFF;
        cnt += (e >= 100 && e <= 140) ? 1 : 0;
    }
    #pragma unroll
    for (int o = 32; o >= 1; o >>= 1) cnt += __shfl_xor(cnt, o);
    if (tid == 0) *flag = (cnt > 2048) ? 1 : 0;
}

// ------------------------------------------------------------- device helpers
__device__ __forceinline__ void dev_convert8(
    const void* src, unsigned short* dst, int isb, int i)
{
    if (isb) {
        *(uint4*)&dst[i] = *(const uint4*)((const unsigned short*)src + i);
    } else {
        const float* s = (const float*)src + i;
        unsigned short v[8];
        #pragma unroll
        for (int j = 0; j < 8; ++j) v[j] = f2bf(s[j]);
        *(uint4*)&dst[i] = *(uint4*)v;
    }
}

// 32x32 transpose(+cvt): reads src[(by*32+r)*C + bx*32+c],
// writes dst[(bx*32+r)*R + by*32+c]
__device__ __forceinline__ void dev_transpose32(
    const void* src, unsigned short* dst, int isb, int R, int C,
    int bx, int by, int tid, unsigned short (*tile)[33])
{
    const int c = tid & 31, r8 = tid >> 5;
    #pragma unroll
    for (int i = 0; i < 4; ++i) {
        int r = r8 + i * 8;
        size_t idx = (size_t)(by * 32 + r) * C + bx * 32 + c;
        tile[r][c] = isb ? ((const unsigned short*)src)[idx]
                         : f2bf(((const float*)src)[idx]);
    }
    __syncthreads();
    #pragma unroll
    for (int i = 0; i < 4; ++i) {
        int r = r8 + i * 8;
        dst[(size_t)(bx * 32 + r) * R + by * 32 + c] = tile[c][r];
    }
}

__device__ __forceinline__ void dev_finalize(
    unsigned short* qkv, const int* segment_pos,
    const void* qs_raw, const void* ks_raw, int isb, int w, int lane)
{
    const int b = w / (T_SEQ * 12);
    const int rem = w % (T_SEQ * 12);
    const int t = rem / 12;
    const int slot = rem % 12;
    const bool isq = slot < 8;
    const int col0 = isq ? slot * 256 : 2048 + (slot - 8) * 256;
    unsigned short* p = qkv + (size_t)(b * T_SEQ + t) * 4096 + col0;

    float e[4];
    #pragma unroll
    for (int j = 0; j < 4; ++j) e[j] = bf2f(p[lane + 64 * j]);
    float ss = e[0] * e[0] + e[1] * e[1] + e[2] * e[2] + e[3] * e[3];
    #pragma unroll
    for (int o = 32; o >= 1; o >>= 1) ss += __shfl_xor(ss, o);
    const float rn = rsqrtf(ss * (1.0f / 256.0f) + 1e-6f);
    const void* scp = isq ? qs_raw : ks_raw;
    float nrm[4];
    #pragma unroll
    for (int j = 0; j < 4; ++j) {
        float sc = isb ? bf2f(((const unsigned short*)scp)[lane + 64 * j])
                       : ((const float*)scp)[lane + 64 * j];
        nrm[j] = e[j] * rn * (1.0f + sc);
    }

    const int pos = segment_pos[b * T_SEQ + t];
    #pragma unroll
    for (int pp = 0; pp < 2; ++pp) {
        const int i = lane + 64 * pp;
        const float inv_ts = __expf((float)i * -0.07195578415606293f);
        float s, c;
        __sincosf((float)pos * inv_ts, &s, &c);
        const float x1 = nrm[pp], x2 = nrm[pp + 2];
        p[i]       = f2bf(x1 * c - x2 * s);
        p[i + 128] = f2bf(x2 * c + x1 * s);
    }
}

__device__ __forceinline__ void dev_build_vt(
    const unsigned short* qkv, unsigned short* vt,
    int bx, int by, int bz, int tid, unsigned short (*tile)[33])
{
    const int bkv = bz;
    const int b = bkv >> 2, kv = bkv & 3;
    const int s0 = bx * 32, d0 = by * 32;
    const int c = tid & 31, r8 = tid >> 5;
    #pragma unroll
    for (int i = 0; i < 4; ++i) {
        int r = r8 + i * 8;
        tile[r][c] = qkv[(size_t)(b * T_SEQ + s0 + r) * 4096 + 3072 + kv * 256 + d0 + c];
    }
    __syncthreads();
    #pragma unroll
    for (int i = 0; i < 4; ++i) {
        int r = r8 + i * 8;
        vt[((size_t)bkv * 256 + d0 + r) * T_SEQ + s0 + c] = tile[c][r];
    }
}

// ------------------------------------------------------------- standalone smalls
// (used by the small-workspace fallback path)
__global__ __launch_bounds__(256) void convert_to_bf16(
    const void* __restrict__ src, unsigned short* __restrict__ dst,
    const int* __restrict__ flag, int n)
{
    int i = (blockIdx.x * 256 + threadIdx.x) * 8;
    if (i >= n) return;
    dev_convert8(src, dst, *flag, i);
}

__global__ __launch_bounds__(256) void transpose_cvt(
    const void* __restrict__ src, unsigned short* __restrict__ dst,
    const int* __restrict__ flag, int R, int C)
{
    __shared__ unsigned short tile[32][33];
    dev_transpose32(src, dst, *flag, R, C, blockIdx.x, blockIdx.y,
                    threadIdx.x, tile);
}

__global__ __launch_bounds__(256) void finalize_qk(
    unsigned short* __restrict__ qkv,
    const int* __restrict__ segment_pos,
    const void* __restrict__ qs_raw,
    const void* __restrict__ ks_raw,
    const int* __restrict__ flag)
{
    dev_finalize(qkv, segment_pos, qs_raw, ks_raw, *flag,
                 blockIdx.x * 4 + (threadIdx.x >> 6), threadIdx.x & 63);
}

__global__ __launch_bounds__(256) void build_vt(
    const unsigned short* __restrict__ qkv, unsigned short* __restrict__ vt)
{
    __shared__ unsigned short tile[32][33];
    dev_build_vt(qkv, vt, blockIdx.x, blockIdx.y, blockIdx.z,
                 threadIdx.x, tile);
}

// ------------------------------------------------------------- fused pre-GEMM
// blocks [0,4096): convert x -> xhat ; [4096,12288): transpose wq/wk/wv -> wT
__global__ __launch_bounds__(256) void prep_fused(
    const void* __restrict__ x,
    const void* __restrict__ wq, const void* __restrict__ wk,
    const void* __restrict__ wv,
    unsigned short* __restrict__ xhat, unsigned short* __restrict__ wT,
    const int* __restrict__ flag)
{
    __shared__ unsigned short tile[32][33];
    const int bid = blockIdx.x;
    const int tid = threadIdx.x;
    const int isb = *flag;
    if (bid < 4096) {
        dev_convert8(x, xhat, isb, (bid * 256 + tid) * 8);
    } else {
        const int k = bid - 4096;
        const int bx = k % 128, by = k / 128;
        const void* src; int C, rowoff, cb;
        if (bx < 64)      { src = wq; C = 2048; rowoff = 0;    cb = bx; }
        else if (bx < 96) { src = wk; C = 1024; rowoff = 2048; cb = bx - 64; }
        else              { src = wv; C = 1024; rowoff = 3072; cb = bx - 96; }
        dev_transpose32(src, wT + (size_t)rowoff * 2048, isb, 2048, C,
                        cb, by, tid, tile);
    }
}

// ------------------------------------------------------------- fused post-GEMM
// [0,12288): finalize Q/K ; [12288,16384): build_vt (V cols, untouched by
// finalize) ; [16384,20480): transpose wo -> woT. All three independent.
__global__ __launch_bounds__(256) void post_fused(
    unsigned short* __restrict__ qkv,
    const int* __restrict__ segment_pos,
    const void* __restrict__ qs_raw, const void* __restrict__ ks_raw,
    unsigned short* __restrict__ vt,
    const void* __restrict__ wo, unsigned short* __restrict__ woT,
    const int* __restrict__ flag)
{
    __shared__ unsigned short tile[32][33];
    const int bid = blockIdx.x;
    const int tid = threadIdx.x;
    if (bid < 12288) {
        dev_finalize(qkv, segment_pos, qs_raw, ks_raw, *flag,
                     bid * 4 + (tid >> 6), tid & 63);
    } else if (bid < 16384) {
        const int k = bid - 12288;
        dev_build_vt(qkv, vt, k % 64, (k / 64) % 8, k / 512, tid, tile);
    } else {
        const int k = bid - 16384;
        dev_transpose32(wo, woT, *flag, 2048, 2048, k % 64, k / 64, tid, tile);
    }
}

// ------------------------------------------------------------- GEMM 128 (m97)
// kept for the small-workspace fallback path
__global__ __launch_bounds__(256) void gemm_bf16(
    const unsigned short* __restrict__ A,
    const unsigned short* __restrict__ Bt,
    void* __restrict__ C,
    int M, int Ntot, int K, int n_base,
    const int* __restrict__ flag, int force_bf16)
{
    __shared__ __align__(16) unsigned short As[128 * 32];
    __shared__ __align__(16) unsigned short Bs[128 * 32];
    const int tid = threadIdx.x;
    const int n0 = blockIdx.x * 128;
    const int m0 = blockIdx.y * 128;
    const int wave = tid >> 6;
    const int lane = tid & 63;
    const int wm = (wave >> 1) * 64;
    const int wn = (wave & 1) * 64;
    const int quad = lane >> 4;
    const int l16 = lane & 15;
    const int obf = force_bf16 | *flag;

    f32x4 acc[4][4];
    #pragma unroll
    for (int i = 0; i < 4; ++i)
        #pragma unroll
        for (int j = 0; j < 4; ++j)
            acc[i][j] = f32x4{0.f, 0.f, 0.f, 0.f};

    for (int kk = 0; kk < K; kk += 32) {
        #pragma unroll
        for (int i = 0; i < 2; ++i) {
            int ch = tid + i * 256;
            int row = ch >> 2;
            int ko = (ch & 3) * 8;
            GLOAD_LDS16(&A[(size_t)(m0 + row) * K + kk + ko],  &As[ch * 8]);
            GLOAD_LDS16(&Bt[(size_t)(n0 + row) * K + kk + ko], &Bs[ch * 8]);
        }
        __syncthreads();
        bf16x8 af[4], bfr[4];
        #pragma unroll
        for (int mi = 0; mi < 4; ++mi)
            af[mi] = *(const bf16x8*)&As[(wm + mi * 16 + l16) * 32 + quad * 8];
        #pragma unroll
        for (int ni = 0; ni < 4; ++ni)
            bfr[ni] = *(const bf16x8*)&Bs[(wn + ni * 16 + l16) * 32 + quad * 8];
        #pragma unroll
        for (int mi = 0; mi < 4; ++mi)
            #pragma unroll
            for (int ni = 0; ni < 4; ++ni)
                acc[mi][ni] = __builtin_amdgcn_mfma_f32_16x16x32_bf16(
                    af[mi], bfr[ni], acc[mi][ni], 0, 0, 0);
        __syncthreads();
    }

    #pragma unroll
    for (int mi = 0; mi < 4; ++mi)
        #pragma unroll
        for (int ni = 0; ni < 4; ++ni)
            #pragma unroll
            for (int r = 0; r < 4; ++r) {
                int row = m0 + wm + mi * 16 + quad * 4 + r;
                int col = n_base + n0 + wn + ni * 16 + l16;
                size_t idx = (size_t)row * Ntot + col;
                if (obf) ((unsigned short*)C)[idx] = f2bf(acc[mi][ni][r]);
                else     ((float*)C)[idx]          = acc[mi][ni][r];
            }
}

// ------------------------------------------------------------- GEMM 256, 8-phase
// (verified R5) m201-style schedule; see R4 notes. Unchanged this round.
__global__ __launch_bounds__(512, 2) void gemm256_bf16(
    const unsigned short* __restrict__ A,
    const unsigned short* __restrict__ Bt,
    void* __restrict__ C,
    int M, int Ntot, int K, int n_base, int gx,
    const int* __restrict__ flag, int force_bf16)
{
    __shared__ __align__(16) unsigned short A_lds[2][256 * 64];
    __shared__ __align__(16) unsigned short B_lds[2][256 * 64];

    const int tid = threadIdx.x;
    const int cpx = gridDim.x >> 3;
    const int swzb = (blockIdx.x & 7) * cpx + (blockIdx.x >> 3);
    const int bx = swzb % gx, by = swzb / gx;
    const int n0 = bx * 256, m0 = by * 256;

    const int wave = tid >> 6, lane = tid & 63;
    const int wr = wave >> 2, wc = wave & 3;          // 2M x 4N
    const int quad = lane >> 4, l16 = lane & 15;
    const int sw7 = l16 & 7;
    const int obf = force_bf16 | *flag;

    const int trow = tid >> 3;            // 0..63
    const int tg   = tid & 7;             // granule 0..7
    const int tsw  = (tg ^ (trow & 7)) * 8;

    f32x4 acc[8][4];
    #pragma unroll
    for (int i = 0; i < 8; ++i)
        #pragma unroll
        for (int j = 0; j < 4; ++j)
            acc[i][j] = f32x4{0.f, 0.f, 0.f, 0.f};

    const int NT = K >> 6;        // K-tiles of 64 (assumed even, >= 4)
    const int NI = NT >> 1;

#define STAGE_A(d_, hm_, kt_)                                                  \
    do { _Pragma("unroll") for (int j = 0; j < 2; ++j) {                       \
        int r_ = j * 128 + (hm_) * 64 + trow;                                  \
        GLOAD_LDS16(&A[(size_t)(m0 + r_) * K + (kt_) * 64 + tsw],              \
                    &A_lds[d_][((hm_) * 128 + j * 64 + trow) * 64 + tg * 8]);  \
    } } while (0)

#define STAGE_B(d_, hn_, kt_)                                                  \
    do { _Pragma("unroll") for (int j = 0; j < 2; ++j) {                       \
        int w2_ = j * 64 + trow;                                               \
        int r_ = (w2_ >> 5) * 64 + (hn_) * 32 + (w2_ & 31);                    \
        GLOAD_LDS16(&Bt[(size_t)(n0 + r_) * K + (kt_) * 64 + tsw],             \
                    &B_lds[d_][((hn_) * 128 + w2_) * 64 + tg * 8]);            \
    } } while (0)

    bf16x8 a[4][2], b0[2][2], b1[2][2];

#define LDA_H(d_, hm_)                                                         \
    do { _Pragma("unroll") for (int mi = 0; mi < 4; ++mi)                      \
         _Pragma("unroll") for (int ks = 0; ks < 2; ++ks)                      \
            a[mi][ks] = *(const bf16x8*)&A_lds[d_][                            \
                ((hm_) * 128 + wr * 64 + mi * 16 + l16) * 64                   \
                + (((ks * 4 + quad) ^ sw7) * 8)]; } while (0)

#define LDB_H(d_, hn_, bb_)                                                    \
    do { _Pragma("unroll") for (int ni = 0; ni < 2; ++ni)                      \
         _Pragma("unroll") for (int ks = 0; ks < 2; ++ks)                      \
            bb_[ni][ks] = *(const bf16x8*)&B_lds[d_][                          \
                ((hn_) * 128 + wc * 32 + ni * 16 + l16) * 64                   \
                + (((ks * 4 + quad) ^ sw7) * 8)]; } while (0)

#define MFMAQ(hm_, hn_, bb_)                                                   \
    do { __builtin_amdgcn_s_setprio(1);                                        \
         _Pragma("unroll") for (int mi = 0; mi < 4; ++mi)                      \
         _Pragma("unroll") for (int ni = 0; ni < 2; ++ni)                      \
         _Pragma("unroll") for (int ks = 0; ks < 2; ++ks)                      \
            acc[(hm_) * 4 + mi][(hn_) * 2 + ni] =                              \
                __builtin_amdgcn_mfma_f32_16x16x32_bf16(                       \
                    a[mi][ks], bb_[ni][ks],                                    \
                    acc[(hm_) * 4 + mi][(hn_) * 2 + ni], 0, 0, 0);             \
         __builtin_amdgcn_s_setprio(0); } while (0)

#define BAR() do { __builtin_amdgcn_sched_barrier(0);                          \
                   __builtin_amdgcn_s_barrier();                               \
                   __builtin_amdgcn_sched_barrier(0); } while (0)
#define LGKM0() do { asm volatile("s_waitcnt lgkmcnt(0)" ::: "memory");        \
                     __builtin_amdgcn_sched_barrier(0); } while (0)
#define VMC(n_) asm volatile("s_waitcnt vmcnt(" #n_ ")" ::: "memory")

    STAGE_A(0, 0, 0); STAGE_B(0, 0, 0); STAGE_B(0, 1, 0); STAGE_A(0, 1, 0);
    STAGE_A(1, 0, 1); STAGE_B(1, 0, 1); STAGE_B(1, 1, 1);
    VMC(6);
    BAR();

    for (int i = 0; i < NI; ++i) {
        const int t2 = 2 * i + 2, t3 = 2 * i + 3;
        const bool s2 = t2 < NT, s3 = t3 < NT;

        LDA_H(0, 0); LDB_H(0, 0, b0);
        STAGE_A(1, 1, 2 * i + 1);
        BAR(); LGKM0(); MFMAQ(0, 0, b0);
        BAR();
        LDB_H(0, 1, b1);
        if (s2) STAGE_A(0, 0, t2);
        BAR(); LGKM0(); MFMAQ(0, 1, b1);
        BAR();
        LDA_H(0, 1);
        if (s2) STAGE_B(0, 0, t2);
        BAR(); LGKM0(); MFMAQ(1, 1, b1);
        BAR();
        if (s2) STAGE_B(0, 1, t2);
        BAR(); LGKM0(); MFMAQ(1, 0, b0);
        if (s2) { VMC(6); } else { VMC(0); }
        BAR();
        LDA_H(1, 0); LDB_H(1, 0, b0);
        if (s2) STAGE_A(0, 1, t2);
        BAR(); LGKM0(); MFMAQ(0, 0, b0);
        BAR();
        LDB_H(1, 1, b1);
        if (s3) STAGE_A(1, 0, t3);
        BAR(); LGKM0(); MFMAQ(0, 1, b1);
        BAR();
        LDA_H(1, 1);
        if (s3) STAGE_B(1, 0, t3);
        BAR(); LGKM0(); MFMAQ(1, 1, b1);
        BAR();
        if (s3) STAGE_B(1, 1, t3);
        BAR(); LGKM0(); MFMAQ(1, 0, b0);
        if (s3) { VMC(6); } else { VMC(0); }
        BAR();
    }

#undef STAGE_A
#undef STAGE_B
#undef LDA_H
#undef LDB_H
#undef MFMAQ
#undef BAR
#undef LGKM0
#undef VMC

    #pragma unroll
    for (int mi = 0; mi < 8; ++mi)
        #pragma unroll
        for (int ni = 0; ni < 4; ++ni)
            #pragma unroll
            for (int r = 0; r < 4; ++r) {
                int row = m0 + wr * 128 + mi * 16 + quad * 4 + r;
                int col = n_base + n0 + wc * 64 + ni * 16 + l16;
                size_t idx = (size_t)row * Ntot + col;
                if (obf) ((unsigned short*)C)[idx] = f2bf(acc[mi][ni][r]);
                else     ((float*)C)[idx]          = acc[mi][ni][r];
            }
}

// ------------------------------------------------------------- MFMA attention
// R5 change: stage K before VT; counted vmcnt(8) gates QK^T (K resident),
// vmcnt(0) drains VT only AFTER QK^T so VT's HBM latency hides under the
// 32-MFMA QK cluster. Barriers are unconditional (outside the per-wave skip).
#define PSTR 80
#define ABAR() do { __builtin_amdgcn_sched_barrier(0);                         \
                    __builtin_amdgcn_s_barrier();                              \
                    __builtin_amdgcn_sched_barrier(0); } while (0)
__global__ __launch_bounds__(256, 2) void attn_mfma(
    const unsigned short* __restrict__ qkv,
    const unsigned short* __restrict__ vt,
    unsigned short* __restrict__ out)
{
    __shared__ __align__(16) unsigned short SMEM[16384 + 16384 + 4 * 16 * PSTR];
    unsigned short* K_lds  = SMEM;            // 64 x 256 (swizzled)
    unsigned short* VT_lds = SMEM + 16384;    // 256 x 64 (swizzled)

    const int tid = threadIdx.x;
    const int wave = tid >> 6, lane = tid & 63;
    const int l16 = lane & 15, quad = lane >> 4;
    const int sw = l16 & 7;
    const int bkv = blockIdx.x & 7;           // XCD swizzle: same bkv -> same XCD
    const int qt  = blockIdx.x >> 3;
    const int b = bkv >> 2, kvh = bkv & 3;
    const int t0 = qt * 32;
    const int h = kvh * 2 + (wave >> 1);
    const int woff = (wave & 1) * 16;
    const int tq = t0 + woff + l16;
    unsigned short* P_lds = SMEM + 32768 + wave * 16 * PSTR;

    bf16x8 qf[8];
    {
        const unsigned short* qp =
            qkv + (size_t)(b * T_SEQ + tq) * 4096 + h * 256 + quad * 8;
        #pragma unroll
        for (int c = 0; c < 8; ++c) qf[c] = *(const bf16x8*)(qp + 32 * c);
    }

    f32x4 o[16];
    #pragma unroll
    for (int nt = 0; nt < 16; ++nt) o[nt] = f32x4{0.f, 0.f, 0.f, 0.f};
    float l_run = 0.f;

    int s_lo = t0 - (WIN - 1); if (s_lo < 0) s_lo = 0;
    const int s_base = s_lo & ~63;
    const int s_last = t0 + 31;
    const int tqmin = t0 + woff;
    const int tqmax = tqmin + 15;
    const int wlo   = tqmin - (WIN - 1);      // lowest key this wave can see
    const size_t kgbase = (size_t)b * T_SEQ * 4096 + 2048 + kvh * 256;
    const size_t vgbase = (size_t)bkv * 256 * T_SEQ;

    for (int sb = s_base; sb <= s_last; sb += 64) {
        ABAR();            // all waves done reading the previous tile

        // K tile first (QK^T needs it); linear LDS dest, pre-swizzled source
        #pragma unroll
        for (int i = 0; i < 8; ++i) {
            int ch = tid + 256 * i;
            int row = ch >> 5, e8 = ch & 31;
            GLOAD_LDS16(&qkv[kgbase + (size_t)(sb + row) * 4096
                             + ((e8 ^ (row & 7)) * 8)],
                        &K_lds[ch * 8]);
        }
        // VT tile second (consumed only by PV)
        #pragma unroll
        for (int i = 0; i < 8; ++i) {
            int ch = tid + 256 * i;
            int dr = ch >> 3, e8 = ch & 7;
            GLOAD_LDS16(&vt[vgbase + (size_t)dr * T_SEQ + sb
                            + ((e8 ^ (dr & 7)) * 8)],
                        &VT_lds[ch * 8]);
        }
        asm volatile("s_waitcnt vmcnt(8)" ::: "memory");   // K's 8 loads landed
        ABAR();                                            // K resident for all

        const bool act = !(sb > tqmax || sb + 63 < wlo);

        f32x4 st[4];
        #pragma unroll
        for (int mt = 0; mt < 4; ++mt) st[mt] = f32x4{0.f, 0.f, 0.f, 0.f};
        if (act) {
            // S^T = K · Q^T
            __builtin_amdgcn_s_setprio(1);
            #pragma unroll
            for (int c = 0; c < 8; ++c) {
                bf16x8 kf[4];
                #pragma unroll
                for (int mt = 0; mt < 4; ++mt)
                    kf[mt] = *(const bf16x8*)&K_lds[(mt * 16 + l16) * 256 + (((4 * c + quad) ^ sw) * 8)];
                #pragma unroll
                for (int mt = 0; mt < 4; ++mt)
                    st[mt] = __builtin_amdgcn_mfma_f32_16x16x32_bf16(kf[mt], qf[c], st[mt], 0, 0, 0);
            }
            __builtin_amdgcn_s_setprio(0);

            // softcap + exp(static m=30); P -> LDS (per-wave region)
            #pragma unroll
            for (int mt = 0; mt < 4; ++mt)
                #pragma unroll
                for (int r = 0; r < 4; ++r) {
                    int sp = sb + mt * 16 + quad * 4 + r;
                    float e2 = __expf(st[mt][r] * 0.0025f);         // exp(2*logits/800)
                    float p = __expf(20.0f - 100.0f / (e2 + 1.0f)); // exp(softcap - 30)
                    bool valid = (sp <= tq) && (tq - sp < WIN);
                    p = valid ? p : 0.0f;
                    l_run += p;
                    P_lds[l16 * PSTR + mt * 16 + quad * 4 + r] = f2bf(p);
                }
        }

        asm volatile("s_waitcnt vmcnt(0)" ::: "memory");   // own VT loads landed
        ABAR();                                            // VT resident for all

        if (act) {
            // O += P · V^T
            #pragma unroll
            for (int c = 0; c < 2; ++c) {
                bf16x8 pf = *(const bf16x8*)&P_lds[l16 * PSTR + 32 * c + quad * 8];
                __builtin_amdgcn_s_setprio(1);
                #pragma unroll
                for (int nt = 0; nt < 16; ++nt) {
                    bf16x8 vf = *(const bf16x8*)&VT_lds[(nt * 16 + l16) * 64 + (((4 * c + quad) ^ sw) * 8)];
                    o[nt] = __builtin_amdgcn_mfma_f32_16x16x32_bf16(pf, vf, o[nt], 0, 0, 0);
                }
                __builtin_amdgcn_s_setprio(0);
            }
        }
    }

    l_run += __shfl_xor(l_run, 16);
    l_run += __shfl_xor(l_run, 32);
    float linv[4];
    #pragma unroll
    for (int r = 0; r < 4; ++r) linv[r] = 1.0f / __shfl(l_run, quad * 4 + r);

    // coalesced epilogue: O -> LDS (row-major 16x256, stride 264) -> dwordx4
    __syncthreads();
    unsigned short* W = SMEM + wave * (16 * 264);
    #pragma unroll
    for (int nt = 0; nt < 16; ++nt)
        #pragma unroll
        for (int r = 0; r < 4; ++r)
            W[(quad * 4 + r) * 264 + nt * 16 + l16] = f2bf(o[nt][r] * linv[r]);
    const int lr = lane >> 2, lc = (lane & 3) * 64;
    unsigned short* ob = out + (size_t)(b * T_SEQ + t0 + woff + lr) * 2048 + h * 256 + lc;
    #pragma unroll
    for (int j = 0; j < 8; ++j)
        *(uint4*)(ob + j * 8) = *(const uint4*)&W[lr * 264 + lc + j * 8];
}

// ------------------------------------------------------------- launch
extern "C" void kernel_launch(void* const* d_in, const int* in_sizes, int n_in,
                              void* d_out, int out_size, void* d_ws, size_t ws_size,
                              hipStream_t stream) {
    const void* x   = d_in[0];
    const int*  sp  = (const int*)d_in[1];
    const void* wq  = d_in[3];
    const void* wk  = d_in[4];
    const void* wv  = d_in[5];
    const void* wo  = d_in[6];
    const void* qsc = d_in[7];
    const void* ksc = d_in[8];

    unsigned short* ws = (unsigned short*)d_ws;
    int*            flag = (int*)ws;
    unsigned short* qkv  = (unsigned short*)d_out;
    dim3 blk(256);

    const size_t NEED = (size_t)(2048 + 8388608 + 8388608) * sizeof(unsigned short);

    detect_dtype<<<1, 64, 0, stream>>>((const unsigned short*)x, flag);

    if (ws_size >= NEED) {
        unsigned short* xhat = ws + 2048;                      // 4096x2048
        unsigned short* wT   = xhat + (size_t)4096 * 2048;     // 4096x2048 stacked
        unsigned short* abuf = xhat;                           // reuse after QKV
        unsigned short* vtb  = wT;                             // reuse after QKV GEMM
        unsigned short* woT  = wT + (size_t)2048 * 2048;       // after vt (4M us)

        // convert x + transpose wq/wk/wv in one launch
        prep_fused<<<12288, blk, 0, stream>>>(x, wq, wk, wv, xhat, wT, flag);

        // fused QKV GEMM, 256^2 8-phase: 16x16 = 256 blocks, 512 threads
        gemm256_bf16<<<256, 512, 0, stream>>>(xhat, wT, qkv,
                                              4096, 4096, 2048, 0, 16, flag, 1);

        // finalize Q/K + build V^T + transpose wo in one launch
        post_fused<<<20480, blk, 0, stream>>>(qkv, sp, qsc, ksc, vtb, wo, woT, flag);

        attn_mfma<<<512, blk, 0, stream>>>(qkv, vtb, abuf);

        // wo GEMM on the 8-phase kernel: 8x16 = 128 blocks (128%8==0)
        gemm256_bf16<<<128, 512, 0, stream>>>(abuf, woT, d_out,
                                              4096, 2048, 2048, 0, 8, flag, 0);
    } else {
        // fallback: two-GEMM layout, ~24.6 MB ws
        unsigned short* reg1 = ws + 2048;                      // 8,388,608 us
        unsigned short* reg2 = reg1 + (size_t)4096 * 2048;     // 4,194,304 us
        unsigned short* xhat = reg1;
        unsigned short* abuf = reg1;

        convert_to_bf16<<<4096, blk, 0, stream>>>(x, xhat, flag, 4096 * 2048);

        transpose_cvt<<<dim3(64, 64), blk, 0, stream>>>(wq, reg2, flag, 2048, 2048);
        gemm_bf16<<<dim3(16, 32), blk, 0, stream>>>(xhat, reg2, qkv,
                                                    4096, 4096, 2048, 0, flag, 1);
        transpose_cvt<<<dim3(32, 64), blk, 0, stream>>>(wk, reg2,                     flag, 2048, 1024);
        transpose_cvt<<<dim3(32, 64), blk, 0, stream>>>(wv, reg2 + (size_t)1024*2048, flag, 2048, 1024);
        gemm_bf16<<<dim3(16, 32), blk, 0, stream>>>(xhat, reg2, qkv,
                                                    4096, 4096, 2048, 2048, flag, 1);

        finalize_qk<<<12288, blk, 0, stream>>>(qkv, sp, qsc, ksc, flag);

        build_vt<<<dim3(64, 8, 8), blk, 0, stream>>>(qkv, reg2);
        attn_mfma<<<512, blk, 0, stream>>>(qkv, reg2, abuf);

        transpose_cvt<<<dim3(64, 64), blk, 0, stream>>>(wo, reg2, flag, 2048, 2048);
        gemm_bf16<<<dim3(16, 32), blk, 0, stream>>>(abuf, reg2, d_out,
                                                    4096, 2048, 2048, 0, flag, 0);
    }
}

// Round 8
// 336.288 us; speedup vs baseline: 1.4359x; 1.0434x over previous
//
#include <hip/hip_runtime.h>

#define T_SEQ 2048
#define NHEADS 8
#define NKV 4
#define HD 256
#define WIN 512

typedef __bf16 bf16x8 __attribute__((ext_vector_type(8)));
typedef float f32x4 __attribute__((ext_vector_type(4)));

__device__ __forceinline__ float bf2f(unsigned short u) {
    return __uint_as_float(((unsigned int)u) << 16);
}
__device__ __forceinline__ unsigned short f2bf(float f) {
    unsigned int u = __float_as_uint(f);
    u += 0x7fffu + ((u >> 16) & 1u);
    return (unsigned short)(u >> 16);
}

#define GLOAD_LDS16(gptr, lptr)                                            \
    __builtin_amdgcn_global_load_lds(                                      \
        (const __attribute__((address_space(1))) unsigned int*)(gptr),     \
        (__attribute__((address_space(3))) unsigned int*)(lptr), 16, 0, 0)

// ------------------------------------------------------------- dtype detect
__global__ void detect_dtype(const unsigned short* __restrict__ x, int* flag) {
    int tid = threadIdx.x;
    int cnt = 0;
    for (int i = 0; i < 64; ++i) {
        unsigned short u = x[2 * (tid * 64 + i)];
        int e = (u >> 7) & 0xFF;
        cnt += (e >= 100 && e <= 140) ? 1 : 0;
    }
    #pragma unroll
    for (int o = 32; o >= 1; o >>= 1) cnt += __shfl_xor(cnt, o);
    if (tid == 0) *flag = (cnt > 2048) ? 1 : 0;
}

// ------------------------------------------------------------- device helpers
__device__ __forceinline__ void dev_convert8(
    const void* src, unsigned short* dst, int isb, int i)
{
    if (isb) {
        *(uint4*)&dst[i] = *(const uint4*)((const unsigned short*)src + i);
    } else {
        const float* s = (const float*)src + i;
        unsigned short v[8];
        #pragma unroll
        for (int j = 0; j < 8; ++j) v[j] = f2bf(s[j]);
        *(uint4*)&dst[i] = *(uint4*)v;
    }
}

__device__ __forceinline__ void dev_transpose32(
    const void* src, unsigned short* dst, int isb, int R, int C,
    int bx, int by, int tid, unsigned short (*tile)[33])
{
    const int c = tid & 31, r8 = tid >> 5;
    #pragma unroll
    for (int i = 0; i < 4; ++i) {
        int r = r8 + i * 8;
        size_t idx = (size_t)(by * 32 + r) * C + bx * 32 + c;
        tile[r][c] = isb ? ((const unsigned short*)src)[idx]
                         : f2bf(((const float*)src)[idx]);
    }
    __syncthreads();
    #pragma unroll
    for (int i = 0; i < 4; ++i) {
        int r = r8 + i * 8;
        dst[(size_t)(bx * 32 + r) * R + by * 32 + c] = tile[c][r];
    }
}

__device__ __forceinline__ void dev_finalize(
    unsigned short* qkv, const int* segment_pos,
    const void* qs_raw, const void* ks_raw, int isb, int w, int lane)
{
    const int b = w / (T_SEQ * 12);
    const int rem = w % (T_SEQ * 12);
    const int t = rem / 12;
    const int slot = rem % 12;
    const bool isq = slot < 8;
    const int col0 = isq ? slot * 256 : 2048 + (slot - 8) * 256;
    unsigned short* p = qkv + (size_t)(b * T_SEQ + t) * 4096 + col0;

    float e[4];
    #pragma unroll
    for (int j = 0; j < 4; ++j) e[j] = bf2f(p[lane + 64 * j]);
    float ss = e[0] * e[0] + e[1] * e[1] + e[2] * e[2] + e[3] * e[3];
    #pragma unroll
    for (int o = 32; o >= 1; o >>= 1) ss += __shfl_xor(ss, o);
    const float rn = rsqrtf(ss * (1.0f / 256.0f) + 1e-6f);
    const void* scp = isq ? qs_raw : ks_raw;
    float nrm[4];
    #pragma unroll
    for (int j = 0; j < 4; ++j) {
        float sc = isb ? bf2f(((const unsigned short*)scp)[lane + 64 * j])
                       : ((const float*)scp)[lane + 64 * j];
        nrm[j] = e[j] * rn * (1.0f + sc);
    }

    const int pos = segment_pos[b * T_SEQ + t];
    #pragma unroll
    for (int pp = 0; pp < 2; ++pp) {
        const int i = lane + 64 * pp;
        const float inv_ts = __expf((float)i * -0.07195578415606293f);
        float s, c;
        __sincosf((float)pos * inv_ts, &s, &c);
        const float x1 = nrm[pp], x2 = nrm[pp + 2];
        p[i]       = f2bf(x1 * c - x2 * s);
        p[i + 128] = f2bf(x2 * c + x1 * s);
    }
}

__device__ __forceinline__ void dev_build_vt(
    const unsigned short* qkv, unsigned short* vt,
    int bx, int by, int bz, int tid, unsigned short (*tile)[33])
{
    const int bkv = bz;
    const int b = bkv >> 2, kv = bkv & 3;
    const int s0 = bx * 32, d0 = by * 32;
    const int c = tid & 31, r8 = tid >> 5;
    #pragma unroll
    for (int i = 0; i < 4; ++i) {
        int r = r8 + i * 8;
        tile[r][c] = qkv[(size_t)(b * T_SEQ + s0 + r) * 4096 + 3072 + kv * 256 + d0 + c];
    }
    __syncthreads();
    #pragma unroll
    for (int i = 0; i < 4; ++i) {
        int r = r8 + i * 8;
        vt[((size_t)bkv * 256 + d0 + r) * T_SEQ + s0 + c] = tile[c][r];
    }
}

// ------------------------------------------------------------- standalone smalls
__global__ __launch_bounds__(256) void convert_to_bf16(
    const void* __restrict__ src, unsigned short* __restrict__ dst,
    const int* __restrict__ flag, int n)
{
    int i = (blockIdx.x * 256 + threadIdx.x) * 8;
    if (i >= n) return;
    dev_convert8(src, dst, *flag, i);
}

__global__ __launch_bounds__(256) void transpose_cvt(
    const void* __restrict__ src, unsigned short* __restrict__ dst,
    const int* __restrict__ flag, int R, int C)
{
    __shared__ unsigned short tile[32][33];
    dev_transpose32(src, dst, *flag, R, C, blockIdx.x, blockIdx.y,
                    threadIdx.x, tile);
}

__global__ __launch_bounds__(256) void finalize_qk(
    unsigned short* __restrict__ qkv,
    const int* __restrict__ segment_pos,
    const void* __restrict__ qs_raw,
    const void* __restrict__ ks_raw,
    const int* __restrict__ flag)
{
    dev_finalize(qkv, segment_pos, qs_raw, ks_raw, *flag,
                 blockIdx.x * 4 + (threadIdx.x >> 6), threadIdx.x & 63);
}

__global__ __launch_bounds__(256) void build_vt(
    const unsigned short* __restrict__ qkv, unsigned short* __restrict__ vt)
{
    __shared__ unsigned short tile[32][33];
    dev_build_vt(qkv, vt, blockIdx.x, blockIdx.y, blockIdx.z,
                 threadIdx.x, tile);
}

// ------------------------------------------------------------- fused pre-GEMM
__global__ __launch_bounds__(256) void prep_fused(
    const void* __restrict__ x,
    const void* __restrict__ wq, const void* __restrict__ wk,
    const void* __restrict__ wv,
    unsigned short* __restrict__ xhat, unsigned short* __restrict__ wT,
    const int* __restrict__ flag)
{
    __shared__ unsigned short tile[32][33];
    const int bid = blockIdx.x;
    const int tid = threadIdx.x;
    const int isb = *flag;
    if (bid < 4096) {
        dev_convert8(x, xhat, isb, (bid * 256 + tid) * 8);
    } else {
        const int k = bid - 4096;
        const int bx = k % 128, by = k / 128;
        const void* src; int C, rowoff, cb;
        if (bx < 64)      { src = wq; C = 2048; rowoff = 0;    cb = bx; }
        else if (bx < 96) { src = wk; C = 1024; rowoff = 2048; cb = bx - 64; }
        else              { src = wv; C = 1024; rowoff = 3072; cb = bx - 96; }
        dev_transpose32(src, wT + (size_t)rowoff * 2048, isb, 2048, C,
                        cb, by, tid, tile);
    }
}

// ------------------------------------------------------------- fused post-GEMM
__global__ __launch_bounds__(256) void post_fused(
    unsigned short* __restrict__ qkv,
    const int* __restrict__ segment_pos,
    const void* __restrict__ qs_raw, const void* __restrict__ ks_raw,
    unsigned short* __restrict__ vt,
    const void* __restrict__ wo, unsigned short* __restrict__ woT,
    const int* __restrict__ flag)
{
    __shared__ unsigned short tile[32][33];
    const int bid = blockIdx.x;
    const int tid = threadIdx.x;
    if (bid < 12288) {
        dev_finalize(qkv, segment_pos, qs_raw, ks_raw, *flag,
                     bid * 4 + (tid >> 6), tid & 63);
    } else if (bid < 16384) {
        const int k = bid - 12288;
        dev_build_vt(qkv, vt, k % 64, (k / 64) % 8, k / 512, tid, tile);
    } else {
        const int k = bid - 16384;
        dev_transpose32(wo, woT, *flag, 2048, 2048, k % 64, k / 64, tid, tile);
    }
}

// ------------------------------------------------------------- GEMM 128 (m97)
// kept for the small-workspace fallback path
__global__ __launch_bounds__(256) void gemm_bf16(
    const unsigned short* __restrict__ A,
    const unsigned short* __restrict__ Bt,
    void* __restrict__ C,
    int M, int Ntot, int K, int n_base,
    const int* __restrict__ flag, int force_bf16)
{
    __shared__ __align__(16) unsigned short As[128 * 32];
    __shared__ __align__(16) unsigned short Bs[128 * 32];
    const int tid = threadIdx.x;
    const int n0 = blockIdx.x * 128;
    const int m0 = blockIdx.y * 128;
    const int wave = tid >> 6;
    const int lane = tid & 63;
    const int wm = (wave >> 1) * 64;
    const int wn = (wave & 1) * 64;
    const int quad = lane >> 4;
    const int l16 = lane & 15;
    const int obf = force_bf16 | *flag;

    f32x4 acc[4][4];
    #pragma unroll
    for (int i = 0; i < 4; ++i)
        #pragma unroll
        for (int j = 0; j < 4; ++j)
            acc[i][j] = f32x4{0.f, 0.f, 0.f, 0.f};

    for (int kk = 0; kk < K; kk += 32) {
        #pragma unroll
        for (int i = 0; i < 2; ++i) {
            int ch = tid + i * 256;
            int row = ch >> 2;
            int ko = (ch & 3) * 8;
            GLOAD_LDS16(&A[(size_t)(m0 + row) * K + kk + ko],  &As[ch * 8]);
            GLOAD_LDS16(&Bt[(size_t)(n0 + row) * K + kk + ko], &Bs[ch * 8]);
        }
        __syncthreads();
        bf16x8 af[4], bfr[4];
        #pragma unroll
        for (int mi = 0; mi < 4; ++mi)
            af[mi] = *(const bf16x8*)&As[(wm + mi * 16 + l16) * 32 + quad * 8];
        #pragma unroll
        for (int ni = 0; ni < 4; ++ni)
            bfr[ni] = *(const bf16x8*)&Bs[(wn + ni * 16 + l16) * 32 + quad * 8];
        #pragma unroll
        for (int mi = 0; mi < 4; ++mi)
            #pragma unroll
            for (int ni = 0; ni < 4; ++ni)
                acc[mi][ni] = __builtin_amdgcn_mfma_f32_16x16x32_bf16(
                    af[mi], bfr[ni], acc[mi][ni], 0, 0, 0);
        __syncthreads();
    }

    #pragma unroll
    for (int mi = 0; mi < 4; ++mi)
        #pragma unroll
        for (int ni = 0; ni < 4; ++ni)
            #pragma unroll
            for (int r = 0; r < 4; ++r) {
                int row = m0 + wm + mi * 16 + quad * 4 + r;
                int col = n_base + n0 + wn + ni * 16 + l16;
                size_t idx = (size_t)row * Ntot + col;
                if (obf) ((unsigned short*)C)[idx] = f2bf(acc[mi][ni][r]);
                else     ((float*)C)[idx]          = acc[mi][ni][r];
            }
}

// ------------------------------------------------------------- GEMM 256, 8-phase
// (verified R5) used for the QKV projection. Unchanged.
__global__ __launch_bounds__(512, 2) void gemm256_bf16(
    const unsigned short* __restrict__ A,
    const unsigned short* __restrict__ Bt,
    void* __restrict__ C,
    int M, int Ntot, int K, int n_base, int gx,
    const int* __restrict__ flag, int force_bf16)
{
    __shared__ __align__(16) unsigned short A_lds[2][256 * 64];
    __shared__ __align__(16) unsigned short B_lds[2][256 * 64];

    const int tid = threadIdx.x;
    const int cpx = gridDim.x >> 3;
    const int swzb = (blockIdx.x & 7) * cpx + (blockIdx.x >> 3);
    const int bx = swzb % gx, by = swzb / gx;
    const int n0 = bx * 256, m0 = by * 256;

    const int wave = tid >> 6, lane = tid & 63;
    const int wr = wave >> 2, wc = wave & 3;          // 2M x 4N
    const int quad = lane >> 4, l16 = lane & 15;
    const int sw7 = l16 & 7;
    const int obf = force_bf16 | *flag;

    const int trow = tid >> 3;            // 0..63
    const int tg   = tid & 7;             // granule 0..7
    const int tsw  = (tg ^ (trow & 7)) * 8;

    f32x4 acc[8][4];
    #pragma unroll
    for (int i = 0; i < 8; ++i)
        #pragma unroll
        for (int j = 0; j < 4; ++j)
            acc[i][j] = f32x4{0.f, 0.f, 0.f, 0.f};

    const int NT = K >> 6;        // K-tiles of 64 (assumed even, >= 4)
    const int NI = NT >> 1;

#define STAGE_A(d_, hm_, kt_)                                                  \
    do { _Pragma("unroll") for (int j = 0; j < 2; ++j) {                       \
        int r_ = j * 128 + (hm_) * 64 + trow;                                  \
        GLOAD_LDS16(&A[(size_t)(m0 + r_) * K + (kt_) * 64 + tsw],              \
                    &A_lds[d_][((hm_) * 128 + j * 64 + trow) * 64 + tg * 8]);  \
    } } while (0)

#define STAGE_B(d_, hn_, kt_)                                                  \
    do { _Pragma("unroll") for (int j = 0; j < 2; ++j) {                       \
        int w2_ = j * 64 + trow;                                               \
        int r_ = (w2_ >> 5) * 64 + (hn_) * 32 + (w2_ & 31);                    \
        GLOAD_LDS16(&Bt[(size_t)(n0 + r_) * K + (kt_) * 64 + tsw],             \
                    &B_lds[d_][((hn_) * 128 + w2_) * 64 + tg * 8]);            \
    } } while (0)

    bf16x8 a[4][2], b0[2][2], b1[2][2];

#define LDA_H(d_, hm_)                                                         \
    do { _Pragma("unroll") for (int mi = 0; mi < 4; ++mi)                      \
         _Pragma("unroll") for (int ks = 0; ks < 2; ++ks)                      \
            a[mi][ks] = *(const bf16x8*)&A_lds[d_][                            \
                ((hm_) * 128 + wr * 64 + mi * 16 + l16) * 64                   \
                + (((ks * 4 + quad) ^ sw7) * 8)]; } while (0)

#define LDB_H(d_, hn_, bb_)                                                    \
    do { _Pragma("unroll") for (int ni = 0; ni < 2; ++ni)                      \
         _Pragma("unroll") for (int ks = 0; ks < 2; ++ks)                      \
            bb_[ni][ks] = *(const bf16x8*)&B_lds[d_][                          \
                ((hn_) * 128 + wc * 32 + ni * 16 + l16) * 64                   \
                + (((ks * 4 + quad) ^ sw7) * 8)]; } while (0)

#define MFMAQ(hm_, hn_, bb_)                                                   \
    do { __builtin_amdgcn_s_setprio(1);                                        \
         _Pragma("unroll") for (int mi = 0; mi < 4; ++mi)                      \
         _Pragma("unroll") for (int ni = 0; ni < 2; ++ni)                      \
         _Pragma("unroll") for (int ks = 0; ks < 2; ++ks)                      \
            acc[(hm_) * 4 + mi][(hn_) * 2 + ni] =                              \
                __builtin_amdgcn_mfma_f32_16x16x32_bf16(                       \
                    a[mi][ks], bb_[ni][ks],                                    \
                    acc[(hm_) * 4 + mi][(hn_) * 2 + ni], 0, 0, 0);             \
         __builtin_amdgcn_s_setprio(0); } while (0)

#define BAR() do { __builtin_amdgcn_sched_barrier(0);                          \
                   __builtin_amdgcn_s_barrier();                               \
                   __builtin_amdgcn_sched_barrier(0); } while (0)
#define LGKM0() do { asm volatile("s_waitcnt lgkmcnt(0)" ::: "memory");        \
                     __builtin_amdgcn_sched_barrier(0); } while (0)
#define VMC(n_) asm volatile("s_waitcnt vmcnt(" #n_ ")" ::: "memory")

    STAGE_A(0, 0, 0); STAGE_B(0, 0, 0); STAGE_B(0, 1, 0); STAGE_A(0, 1, 0);
    STAGE_A(1, 0, 1); STAGE_B(1, 0, 1); STAGE_B(1, 1, 1);
    VMC(6);
    BAR();

    for (int i = 0; i < NI; ++i) {
        const int t2 = 2 * i + 2, t3 = 2 * i + 3;
        const bool s2 = t2 < NT, s3 = t3 < NT;

        LDA_H(0, 0); LDB_H(0, 0, b0);
        STAGE_A(1, 1, 2 * i + 1);
        BAR(); LGKM0(); MFMAQ(0, 0, b0);
        BAR();
        LDB_H(0, 1, b1);
        if (s2) STAGE_A(0, 0, t2);
        BAR(); LGKM0(); MFMAQ(0, 1, b1);
        BAR();
        LDA_H(0, 1);
        if (s2) STAGE_B(0, 0, t2);
        BAR(); LGKM0(); MFMAQ(1, 1, b1);
        BAR();
        if (s2) STAGE_B(0, 1, t2);
        BAR(); LGKM0(); MFMAQ(1, 0, b0);
        if (s2) { VMC(6); } else { VMC(0); }
        BAR();
        LDA_H(1, 0); LDB_H(1, 0, b0);
        if (s2) STAGE_A(0, 1, t2);
        BAR(); LGKM0(); MFMAQ(0, 0, b0);
        BAR();
        LDB_H(1, 1, b1);
        if (s3) STAGE_A(1, 0, t3);
        BAR(); LGKM0(); MFMAQ(0, 1, b1);
        BAR();
        LDA_H(1, 1);
        if (s3) STAGE_B(1, 0, t3);
        BAR(); LGKM0(); MFMAQ(1, 1, b1);
        BAR();
        if (s3) STAGE_B(1, 1, t3);
        BAR(); LGKM0(); MFMAQ(1, 0, b0);
        if (s3) { VMC(6); } else { VMC(0); }
        BAR();
    }

#undef STAGE_A
#undef STAGE_B
#undef LDA_H
#undef LDB_H
#undef MFMAQ
#undef BAR
#undef LGKM0
#undef VMC

    #pragma unroll
    for (int mi = 0; mi < 8; ++mi)
        #pragma unroll
        for (int ni = 0; ni < 4; ++ni)
            #pragma unroll
            for (int r = 0; r < 4; ++r) {
                int row = m0 + wr * 128 + mi * 16 + quad * 4 + r;
                int col = n_base + n0 + wc * 64 + ni * 16 + l16;
                size_t idx = (size_t)row * Ntot + col;
                if (obf) ((unsigned short*)C)[idx] = f2bf(acc[mi][ni][r]);
                else     ((float*)C)[idx]          = acc[mi][ni][r];
            }
}

// ------------------------------------------------------------- GEMM 256x128
// BM=256, BN=128, BK=64, 8 waves (2M x 4N), acc[8][2]. For N=2048 outputs this
// doubles the grid (16x16=256 blocks) vs the 256^2 kernel's 128 -> all CUs
// busy. Schedule = R4-verified simple pattern. LDS 96 KiB (1 block/CU).
__global__ __launch_bounds__(512, 2) void gemm128n_bf16(
    const unsigned short* __restrict__ A,
    const unsigned short* __restrict__ Bt,
    void* __restrict__ C,
    int M, int Ntot, int K, int n_base, int gx,
    const int* __restrict__ flag, int force_bf16)
{
    __shared__ __align__(16) unsigned short A_lds[2][256 * 64];
    __shared__ __align__(16) unsigned short B_lds[2][128 * 64];

    const int tid = threadIdx.x;
    const int cpx = gridDim.x >> 3;
    const int swzb = (blockIdx.x & 7) * cpx + (blockIdx.x >> 3);
    const int bx = swzb % gx, by = swzb / gx;
    const int n0 = bx * 128, m0 = by * 256;

    const int wave = tid >> 6, lane = tid & 63;
    const int wr = wave >> 2, wc = wave & 3;          // 2M x 4N
    const int quad = lane >> 4, l16 = lane & 15;
    const int sw7 = l16 & 7;
    const int obf = force_bf16 | *flag;

    const int r0 = tid >> 3;                          // 0..63
    const int chs = ((tid & 7) ^ (r0 & 7)) * 8;       // pre-swizzled col
    const unsigned short* Ab = A  + (size_t)(m0 + r0) * K + chs;
    const unsigned short* Bb = Bt + (size_t)(n0 + r0) * K + chs;

    f32x4 acc[8][2];
    #pragma unroll
    for (int i = 0; i < 8; ++i)
        #pragma unroll
        for (int j = 0; j < 2; ++j)
            acc[i][j] = f32x4{0.f, 0.f, 0.f, 0.f};

    const int NT = K >> 6;

#define STAGE_N(buf_, kt_)                                                \
    do {                                                                  \
        _Pragma("unroll")                                                 \
        for (int j = 0; j < 4; ++j)                                       \
            GLOAD_LDS16(Ab + (size_t)(64 * j) * K + (size_t)(kt_) * 64,   \
                        &A_lds[buf_][(tid + 512 * j) * 8]);               \
        _Pragma("unroll")                                                 \
        for (int j = 0; j < 2; ++j)                                       \
            GLOAD_LDS16(Bb + (size_t)(64 * j) * K + (size_t)(kt_) * 64,   \
                        &B_lds[buf_][(tid + 512 * j) * 8]);               \
    } while (0)

    STAGE_N(0, 0);
    __syncthreads();                     // implicit vmcnt(0): tile0 resident

    for (int t = 0; t < NT; ++t) {
        const int cb = t & 1;
        if (t + 1 < NT) STAGE_N(cb ^ 1, t + 1);   // lands during this tile

        const unsigned short* Ac = A_lds[cb];
        const unsigned short* Bc = B_lds[cb];
        bf16x8 a4[4][2], b2[2][2];

        #pragma unroll
        for (int ni = 0; ni < 2; ++ni)
            #pragma unroll
            for (int ks = 0; ks < 2; ++ks)
                b2[ni][ks] = *(const bf16x8*)&Bc[(wc * 32 + ni * 16 + l16) * 64
                                                + (((ks * 4 + quad) ^ sw7) * 8)];

        // ---- SP0: rows 0-63 of the wave footprint
        #pragma unroll
        for (int mi = 0; mi < 4; ++mi)
            #pragma unroll
            for (int ks = 0; ks < 2; ++ks)
                a4[mi][ks] = *(const bf16x8*)&Ac[(wr * 128 + mi * 16 + l16) * 64
                                                + (((ks * 4 + quad) ^ sw7) * 8)];
        __builtin_amdgcn_s_setprio(1);
        #pragma unroll
        for (int mi = 0; mi < 4; ++mi)
            #pragma unroll
            for (int ni = 0; ni < 2; ++ni)
                #pragma unroll
                for (int ks = 0; ks < 2; ++ks)
                    acc[mi][ni] = __builtin_amdgcn_mfma_f32_16x16x32_bf16(
                        a4[mi][ks], b2[ni][ks], acc[mi][ni], 0, 0, 0);
        __builtin_amdgcn_s_setprio(0);

        // ---- SP1: rows 64-127
        #pragma unroll
        for (int mi = 0; mi < 4; ++mi)
            #pragma unroll
            for (int ks = 0; ks < 2; ++ks)
                a4[mi][ks] = *(const bf16x8*)&Ac[(wr * 128 + (mi + 4) * 16 + l16) * 64
                                                + (((ks * 4 + quad) ^ sw7) * 8)];
        __builtin_amdgcn_s_setprio(1);
        #pragma unroll
        for (int mi = 0; mi < 4; ++mi)
            #pragma unroll
            for (int ni = 0; ni < 2; ++ni)
                #pragma unroll
                for (int ks = 0; ks < 2; ++ks)
                    acc[mi + 4][ni] = __builtin_amdgcn_mfma_f32_16x16x32_bf16(
                        a4[mi][ks], b2[ni][ks], acc[mi + 4][ni], 0, 0, 0);
        __builtin_amdgcn_s_setprio(0);

        __syncthreads();   // drains vmcnt(0): tile t+1 resident, tile t closed
    }
#undef STAGE_N

    #pragma unroll
    for (int mi = 0; mi < 8; ++mi)
        #pragma unroll
        for (int ni = 0; ni < 2; ++ni)
            #pragma unroll
            for (int r = 0; r < 4; ++r) {
                int row = m0 + wr * 128 + mi * 16 + quad * 4 + r;
                int col = n_base + n0 + wc * 32 + ni * 16 + l16;
                size_t idx = (size_t)row * Ntot + col;
                if (obf) ((unsigned short*)C)[idx] = f2bf(acc[mi][ni][r]);
                else     ((float*)C)[idx]          = acc[mi][ni][r];
            }
}

// ------------------------------------------------------------- MFMA attention
#define PSTR 80
#define ABAR() do { __builtin_amdgcn_sched_barrier(0);                         \
                    __builtin_amdgcn_s_barrier();                              \
                    __builtin_amdgcn_sched_barrier(0); } while (0)
__global__ __launch_bounds__(256, 2) void attn_mfma(
    const unsigned short* __restrict__ qkv,
    const unsigned short* __restrict__ vt,
    unsigned short* __restrict__ out)
{
    __shared__ __align__(16) unsigned short SMEM[16384 + 16384 + 4 * 16 * PSTR];
    unsigned short* K_lds  = SMEM;            // 64 x 256 (swizzled)
    unsigned short* VT_lds = SMEM + 16384;    // 256 x 64 (swizzled)

    const int tid = threadIdx.x;
    const int wave = tid >> 6, lane = tid & 63;
    const int l16 = lane & 15, quad = lane >> 4;
    const int sw = l16 & 7;
    const int bkv = blockIdx.x & 7;           // XCD swizzle: same bkv -> same XCD
    const int qt  = blockIdx.x >> 3;
    const int b = bkv >> 2, kvh = bkv & 3;
    const int t0 = qt * 32;
    const int h = kvh * 2 + (wave >> 1);
    const int woff = (wave & 1) * 16;
    const int tq = t0 + woff + l16;
    unsigned short* P_lds = SMEM + 32768 + wave * 16 * PSTR;

    bf16x8 qf[8];
    {
        const unsigned short* qp =
            qkv + (size_t)(b * T_SEQ + tq) * 4096 + h * 256 + quad * 8;
        #pragma unroll
        for (int c = 0; c < 8; ++c) qf[c] = *(const bf16x8*)(qp + 32 * c);
    }

    f32x4 o[16];
    #pragma unroll
    for (int nt = 0; nt < 16; ++nt) o[nt] = f32x4{0.f, 0.f, 0.f, 0.f};
    float l_run = 0.f;

    int s_lo = t0 - (WIN - 1); if (s_lo < 0) s_lo = 0;
    const int s_base = s_lo & ~63;
    const int s_last = t0 + 31;
    const int tqmin = t0 + woff;
    const int tqmax = tqmin + 15;
    const int wlo   = tqmin - (WIN - 1);      // lowest key this wave can see
    const size_t kgbase = (size_t)b * T_SEQ * 4096 + 2048 + kvh * 256;
    const size_t vgbase = (size_t)bkv * 256 * T_SEQ;

    for (int sb = s_base; sb <= s_last; sb += 64) {
        ABAR();            // all waves done reading the previous tile

        // K tile first (QK^T needs it); linear LDS dest, pre-swizzled source
        #pragma unroll
        for (int i = 0; i < 8; ++i) {
            int ch = tid + 256 * i;
            int row = ch >> 5, e8 = ch & 31;
            GLOAD_LDS16(&qkv[kgbase + (size_t)(sb + row) * 4096
                             + ((e8 ^ (row & 7)) * 8)],
                        &K_lds[ch * 8]);
        }
        // VT tile second (consumed only by PV)
        #pragma unroll
        for (int i = 0; i < 8; ++i) {
            int ch = tid + 256 * i;
            int dr = ch >> 3, e8 = ch & 7;
            GLOAD_LDS16(&vt[vgbase + (size_t)dr * T_SEQ + sb
                            + ((e8 ^ (dr & 7)) * 8)],
                        &VT_lds[ch * 8]);
        }
        asm volatile("s_waitcnt vmcnt(8)" ::: "memory");   // K's 8 loads landed
        ABAR();                                            // K resident for all

        const bool act = !(sb > tqmax || sb + 63 < wlo);

        f32x4 st[4];
        #pragma unroll
        for (int mt = 0; mt < 4; ++mt) st[mt] = f32x4{0.f, 0.f, 0.f, 0.f};
        if (act) {
            // S^T = K · Q^T
            __builtin_amdgcn_s_setprio(1);
            #pragma unroll
            for (int c = 0; c < 8; ++c) {
                bf16x8 kf[4];
                #pragma unroll
                for (int mt = 0; mt < 4; ++mt)
                    kf[mt] = *(const bf16x8*)&K_lds[(mt * 16 + l16) * 256 + (((4 * c + quad) ^ sw) * 8)];
                #pragma unroll
                for (int mt = 0; mt < 4; ++mt)
                    st[mt] = __builtin_amdgcn_mfma_f32_16x16x32_bf16(kf[mt], qf[c], st[mt], 0, 0, 0);
            }
            __builtin_amdgcn_s_setprio(0);

            // softcap + exp(static m=30); P -> LDS (per-wave region)
            #pragma unroll
            for (int mt = 0; mt < 4; ++mt)
                #pragma unroll
                for (int r = 0; r < 4; ++r) {
                    int sp = sb + mt * 16 + quad * 4 + r;
                    float e2 = __expf(st[mt][r] * 0.0025f);         // exp(2*logits/800)
                    float p = __expf(20.0f - 100.0f / (e2 + 1.0f)); // exp(softcap - 30)
                    bool valid = (sp <= tq) && (tq - sp < WIN);
                    p = valid ? p : 0.0f;
                    l_run += p;
                    P_lds[l16 * PSTR + mt * 16 + quad * 4 + r] = f2bf(p);
                }
        }

        asm volatile("s_waitcnt vmcnt(0)" ::: "memory");   // own VT loads landed
        ABAR();                                            // VT resident for all

        if (act) {
            // O += P · V^T
            #pragma unroll
            for (int c = 0; c < 2; ++c) {
                bf16x8 pf = *(const bf16x8*)&P_lds[l16 * PSTR + 32 * c + quad * 8];
                __builtin_amdgcn_s_setprio(1);
                #pragma unroll
                for (int nt = 0; nt < 16; ++nt) {
                    bf16x8 vf = *(const bf16x8*)&VT_lds[(nt * 16 + l16) * 64 + (((4 * c + quad) ^ sw) * 8)];
                    o[nt] = __builtin_amdgcn_mfma_f32_16x16x32_bf16(pf, vf, o[nt], 0, 0, 0);
                }
                __builtin_amdgcn_s_setprio(0);
            }
        }
    }

    l_run += __shfl_xor(l_run, 16);
    l_run += __shfl_xor(l_run, 32);
    float linv[4];
    #pragma unroll
    for (int r = 0; r < 4; ++r) linv[r] = 1.0f / __shfl(l_run, quad * 4 + r);

    // coalesced epilogue: O -> LDS (row-major 16x256, stride 264) -> dwordx4
    __syncthreads();
    unsigned short* W = SMEM + wave * (16 * 264);
    #pragma unroll
    for (int nt = 0; nt < 16; ++nt)
        #pragma unroll
        for (int r = 0; r < 4; ++r)
            W[(quad * 4 + r) * 264 + nt * 16 + l16] = f2bf(o[nt][r] * linv[r]);
    const int lr = lane >> 2, lc = (lane & 3) * 64;
    unsigned short* ob = out + (size_t)(b * T_SEQ + t0 + woff + lr) * 2048 + h * 256 + lc;
    #pragma unroll
    for (int j = 0; j < 8; ++j)
        *(uint4*)(ob + j * 8) = *(const uint4*)&W[lr * 264 + lc + j * 8];
}

// ------------------------------------------------------------- launch
extern "C" void kernel_launch(void* const* d_in, const int* in_sizes, int n_in,
                              void* d_out, int out_size, void* d_ws, size_t ws_size,
                              hipStream_t stream) {
    const void* x   = d_in[0];
    const int*  sp  = (const int*)d_in[1];
    const void* wq  = d_in[3];
    const void* wk  = d_in[4];
    const void* wv  = d_in[5];
    const void* wo  = d_in[6];
    const void* qsc = d_in[7];
    const void* ksc = d_in[8];

    unsigned short* ws = (unsigned short*)d_ws;
    int*            flag = (int*)ws;
    unsigned short* qkv  = (unsigned short*)d_out;
    dim3 blk(256);

    const size_t NEED = (size_t)(2048 + 8388608 + 8388608) * sizeof(unsigned short);

    detect_dtype<<<1, 64, 0, stream>>>((const unsigned short*)x, flag);

    if (ws_size >= NEED) {
        unsigned short* xhat = ws + 2048;                      // 4096x2048
        unsigned short* wT   = xhat + (size_t)4096 * 2048;     // 4096x2048 stacked
        unsigned short* abuf = xhat;                           // reuse after QKV
        unsigned short* vtb  = wT;                             // reuse after QKV GEMM
        unsigned short* woT  = wT + (size_t)2048 * 2048;       // after vt (4M us)

        // convert x + transpose wq/wk/wv in one launch
        prep_fused<<<12288, blk, 0, stream>>>(x, wq, wk, wv, xhat, wT, flag);

        // fused QKV GEMM, 256^2 8-phase: 16x16 = 256 blocks, 512 threads
        gemm256_bf16<<<256, 512, 0, stream>>>(xhat, wT, qkv,
                                              4096, 4096, 2048, 0, 16, flag, 1);

        // finalize Q/K + build V^T + transpose wo in one launch
        post_fused<<<20480, blk, 0, stream>>>(qkv, sp, qsc, ksc, vtb, wo, woT, flag);

        attn_mfma<<<512, blk, 0, stream>>>(qkv, vtb, abuf);

        // wo GEMM on the 256x128 kernel: 16x16 = 256 blocks, all CUs busy
        gemm128n_bf16<<<256, 512, 0, stream>>>(abuf, woT, d_out,
                                               4096, 2048, 2048, 0, 16, flag, 0);
    } else {
        // fallback: two-GEMM layout, ~24.6 MB ws
        unsigned short* reg1 = ws + 2048;                      // 8,388,608 us
        unsigned short* reg2 = reg1 + (size_t)4096 * 2048;     // 4,194,304 us
        unsigned short* xhat = reg1;
        unsigned short* abuf = reg1;

        convert_to_bf16<<<4096, blk, 0, stream>>>(x, xhat, flag, 4096 * 2048);

        transpose_cvt<<<dim3(64, 64), blk, 0, stream>>>(wq, reg2, flag, 2048, 2048);
        gemm_bf16<<<dim3(16, 32), blk, 0, stream>>>(xhat, reg2, qkv,
                                                    4096, 4096, 2048, 0, flag, 1);
        transpose_cvt<<<dim3(32, 64), blk, 0, stream>>>(wk, reg2,                     flag, 2048, 1024);
        transpose_cvt<<<dim3(32, 64), blk, 0, stream>>>(wv, reg2 + (size_t)1024*2048, flag, 2048, 1024);
        gemm_bf16<<<dim3(16, 32), blk, 0, stream>>>(xhat, reg2, qkv,
                                                    4096, 4096, 2048, 2048, flag, 1);

        finalize_qk<<<12288, blk, 0, stream>>>(qkv, sp, qsc, ksc, flag);

        build_vt<<<dim3(64, 8, 8), blk, 0, stream>>>(qkv, reg2);
        attn_mfma<<<512, blk, 0, stream>>>(qkv, reg2, abuf);

        transpose_cvt<<<dim3(64, 64), blk, 0, stream>>>(wo, reg2, flag, 2048, 2048);
        gemm_bf16<<<dim3(16, 32), blk, 0, stream>>>(abuf, reg2, d_out,
                                                    4096, 2048, 2048, 0, flag, 0);
    }
}